// Round 9
// baseline (1378.975 us; speedup 1.0000x reference)
//
#include <hip/hip_runtime.h>

#define BB   2048
#define NNX  64
#define DD   256
#define KKC  32
#define LLN  2
#define HHN  8
#define DHH  32
#define DFFN 1024
#define BNT  (BB*NNX)   // 131072

typedef short s16x8 __attribute__((ext_vector_type(8)));
typedef float f32x4 __attribute__((ext_vector_type(4)));

#define GLOAD_LDS16(gp, lp) __builtin_amdgcn_global_load_lds( \
    (const __attribute__((address_space(1))) void*)(gp),      \
    (__attribute__((address_space(3))) void*)(lp), 16, 0, 0)

#define WAITVM5() asm volatile("s_waitcnt vmcnt(5)" ::: "memory")
#define WAITVM4() asm volatile("s_waitcnt vmcnt(4)" ::: "memory")
#define WAITVM0() asm volatile("s_waitcnt vmcnt(0)" ::: "memory")
#define SBAR() __builtin_amdgcn_s_barrier()

__device__ __forceinline__ unsigned short f2bf(float f) {
  unsigned int u = __float_as_uint(f);
  u += 0x7fffu + ((u >> 16) & 1u);   // RNE
  return (unsigned short)(u >> 16);
}
__device__ __forceinline__ float bf2f(unsigned short u) {
  return __uint_as_float(((unsigned int)u) << 16);
}

// ---------------- f32 -> bf16 bulk convert ----------------
__global__ __launch_bounds__(256) void cvt_kernel(const float4* __restrict__ src,
                                                  ushort4* __restrict__ dst, int n4) {
  int i = blockIdx.x * 256 + threadIdx.x;
  int st = gridDim.x * 256;
  for (; i < n4; i += st) {
    float4 v = src[i];
    ushort4 o;
    o.x = f2bf(v.x); o.y = f2bf(v.y); o.z = f2bf(v.z); o.w = f2bf(v.w);
    dst[i] = o;
  }
}

// ---------------- tanh(mu) table (transposed) ----------------
__global__ void mt_kernel(const float* __restrict__ mus, float* __restrict__ mtT,
                          float* __restrict__ mtn) {
  int k = threadIdx.x;
  if (k < 32) {
    float acc = 0.f;
    for (int d = 0; d < 256; d++) {
      float t = tanhf(mus[k * 256 + d]);
      mtT[d * 32 + k] = t;
      acc += t * t;
    }
    mtn[k] = acc;
  }
}

// ---------------- prob_pi, prob_A, zero entropy ----------------
__global__ void piA_kernel(const float* __restrict__ il, const float* __restrict__ tl,
                           float* __restrict__ d_pi, float* __restrict__ d_A,
                           float* __restrict__ d_ent) {
  int lane = threadIdx.x;
  if (lane == 0) *d_ent = 0.f;
  if (lane < 32) {
    float v = il[lane];
    float mx = v;
    #pragma unroll
    for (int off = 16; off; off >>= 1) mx = fmaxf(mx, __shfl_xor(mx, off, 32));
    float e = expf(v - mx), sm = e;
    #pragma unroll
    for (int off = 16; off; off >>= 1) sm += __shfl_xor(sm, off, 32);
    d_pi[lane] = e / sm;
    for (int r = 0; r < 32; r++) {
      float a = tl[r * 32 + lane];
      float m2 = a;
      #pragma unroll
      for (int off = 16; off; off >>= 1) m2 = fmaxf(m2, __shfl_xor(m2, off, 32));
      float e2 = expf(a - m2), s2 = e2;
      #pragma unroll
      for (int off = 16; off; off >>= 1) s2 += __shfl_xor(s2, off, 32);
      d_A[r * 32 + lane] = e2 / s2;
    }
  }
}

// ======== 128x128 tile, BK=32, 4-wave, counted-vmcnt pipelined NT GEMM ========
// (R7-proven, unchanged) EPI 0: bf16 out; 1: relu->bf16.
template <int EPI>
__global__ __launch_bounds__(256, 4) void gemm_nt(const unsigned short* __restrict__ A,
                                                  const unsigned short* __restrict__ Bw,
                                                  const float* __restrict__ bias,
                                                  unsigned short* __restrict__ outp,
                                                  int N, int K, int nx) {
  __shared__ unsigned short lds[16384];   // 32 KB: [2 buf][A 4096 | B 4096]
  const int t = threadIdx.x;
  const int bid = blockIdx.x, nwg = gridDim.x;
  const int wg = (bid & 7) * (nwg >> 3) + (bid >> 3);   // nwg % 8 == 0
  const int m0 = (wg / nx) << 7;
  const int n0 = (wg % nx) << 7;
  const int lane = t & 63, w = t >> 6;
  const int wm = w >> 1, wn = w & 1;      // 2x2 waves, wave tile 64x64
  const int lr = lane & 15, lk = lane >> 4;

  const int r0 = t >> 2, sg = t & 3;
  const int s0 = sg ^ ((r0 >> 1) & 3);
  const int r1 = r0 + 64;
  const int s1 = sg ^ ((r1 >> 1) & 3);
  const int aoff0 = (m0 + r0) * K + s0 * 8;
  const int aoff1 = (m0 + r1) * K + s1 * 8;
  const int boff0 = (n0 + r0) * K + s0 * 8;
  const int boff1 = (n0 + r1) * K + s1 * 8;

#define STAGE(buf, k0) do {                                    \
    char* la = (char*)lds + (buf) * 16384;                     \
    GLOAD_LDS16(A + aoff0 + (k0), la + t * 16);                \
    GLOAD_LDS16(A + aoff1 + (k0), la + 4096 + t * 16);         \
    GLOAD_LDS16(Bw + boff0 + (k0), la + 8192 + t * 16);        \
    GLOAD_LDS16(Bw + boff1 + (k0), la + 12288 + t * 16);       \
  } while (0)

  f32x4 acc[4][4];
  #pragma unroll
  for (int i = 0; i < 4; i++)
    #pragma unroll
    for (int j = 0; j < 4; j++) acc[i][j] = (f32x4)(0.f);

  const int ra = wm * 64 + lr, rb = wn * 64 + lr;
  const int sla = lk ^ ((ra >> 1) & 3), slb = lk ^ ((rb >> 1) & 3);

  const int NT = K >> 5;
  STAGE(0, 0);
  STAGE(1, 32);
  WAITVM4();
  SBAR();

  int c = 0;
  for (int kt = 0; kt < NT; kt++) {
    s16x8 af[4], bf[4];
    {
      const unsigned short* ua = lds + c * 8192;
      const unsigned short* ub = ua + 4096;
      #pragma unroll
      for (int mf = 0; mf < 4; mf++)
        af[mf] = *(const s16x8*)&ua[(ra + mf * 16) * 32 + sla * 8];
      #pragma unroll
      for (int nf = 0; nf < 4; nf++)
        bf[nf] = *(const s16x8*)&ub[(rb + nf * 16) * 32 + slb * 8];
    }
    __builtin_amdgcn_s_setprio(1);
    #pragma unroll
    for (int mf = 0; mf < 4; mf++)
      #pragma unroll
      for (int nf = 0; nf < 4; nf++)
        acc[mf][nf] = __builtin_amdgcn_mfma_f32_16x16x32_bf16(af[mf], bf[nf], acc[mf][nf], 0, 0, 0);
    __builtin_amdgcn_s_setprio(0);
    SBAR();
    if (kt < NT - 2) {
      STAGE(c, (kt + 2) << 5);
      WAITVM4();
    } else if (kt == NT - 2) {
      WAITVM0();
    }
    SBAR();
    c ^= 1;
  }
#undef STAGE

  #pragma unroll
  for (int nf = 0; nf < 4; nf++) {
    int col = n0 + wn * 64 + nf * 16 + lr;
    float bv = bias[col];
    #pragma unroll
    for (int mf = 0; mf < 4; mf++)
      #pragma unroll
      for (int r = 0; r < 4; r++) {
        int row = m0 + wm * 64 + mf * 16 + lk * 4 + r;
        float v = acc[mf][nf][r] + bv;
        if (EPI == 1) v = fmaxf(v, 0.f);
        outp[(size_t)row * N + col] = f2bf(v);
      }
  }
}

// == 64x256 (full width) pipelined GEMM + bias + residual + LayerNorm ==
// 256 thr / 4 waves (1M x 4N), wave tile 64x64 -- mirrors the validated
// gemm_nt regime (4 blocks/CU at (256,4), counted vmcnt). LDS: 2 bufs x
// (A[64][32] + B[256][32]) = 40 KB. Slot-XOR swizzle (all fragment rows
// give slot = lk ^ ((lr>>1)&3)). 5 loads/STAGE -> vmcnt(5) steady state.
// Stats unioned into LDS after the K-loop. WR32: also write f32 x32.
template <bool WR32>
__global__ __launch_bounds__(256, 4) void gemm_ln(const unsigned short* __restrict__ A,
                                                  const unsigned short* __restrict__ Bw,
                                                  const float* __restrict__ bias,
                                                  const unsigned short* __restrict__ res,
                                                  const float* __restrict__ g,
                                                  const float* __restrict__ bta,
                                                  unsigned short* __restrict__ xb,
                                                  float* __restrict__ x32,
                                                  int K) {
  __shared__ unsigned short lds[20480];   // 40 KB: [2 buf][A 2048 | B 8192] shorts
  float* stats = (float*)lds;             // [2][64][4] = 2 KB, post-loop only
  const int t = threadIdx.x;
  const int bid = blockIdx.x, nwg = gridDim.x;
  const int wg = (bid & 7) * (nwg >> 3) + (bid >> 3);   // nwg = 2048
  const int m0 = wg << 6;

  const int lane = t & 63, w = t >> 6;
  const int wn = w;                       // 1M x 4N waves; wave tile 64x64
  const int lr = lane & 15, lk = lane >> 4;

  // staging: A row r0=t>>2 (0..63); B rows p*64+r0 (p=0..3). Slot XOR is
  // invariant under +64 rows ((64>>1)&3 == 0), so one s0 serves all.
  const int r0 = t >> 2, sg = t & 3;
  const int s0 = sg ^ ((r0 >> 1) & 3);
  const int aoff = (m0 + r0) * K + s0 * 8;
  const int boff0 = (r0 +   0) * K + s0 * 8;
  const int boff1 = (r0 +  64) * K + s0 * 8;
  const int boff2 = (r0 + 128) * K + s0 * 8;
  const int boff3 = (r0 + 192) * K + s0 * 8;

#define STAGE(buf, k0) do {                                      \
    char* la = (char*)lds + (buf) * 20480;                       \
    GLOAD_LDS16(A + aoff + (k0),   la + t * 16);                 \
    GLOAD_LDS16(Bw + boff0 + (k0), la + 4096 + t * 16);          \
    GLOAD_LDS16(Bw + boff1 + (k0), la + 8192 + t * 16);          \
    GLOAD_LDS16(Bw + boff2 + (k0), la + 12288 + t * 16);         \
    GLOAD_LDS16(Bw + boff3 + (k0), la + 16384 + t * 16);         \
  } while (0)

  f32x4 acc[4][4];
  #pragma unroll
  for (int i = 0; i < 4; i++)
    #pragma unroll
    for (int j = 0; j < 4; j++) acc[i][j] = (f32x4)(0.f);

  // fragment rows: A ra = mf*16+lr, B rb = wn*64+nf*16+lr -> slot invariant
  const int sl = lk ^ ((lr >> 1) & 3);
  const int rb = wn * 64 + lr;

  const int NT = K >> 5;
  STAGE(0, 0);
  STAGE(1, 32);
  WAITVM5();     // tile 0 resident (tile 1's 5 loads may still fly)
  SBAR();

  int c = 0;
  for (int kt = 0; kt < NT; kt++) {
    s16x8 af[4], bf[4];
    {
      const unsigned short* ua = lds + c * 10240;
      const unsigned short* ub = ua + 2048;
      #pragma unroll
      for (int mf = 0; mf < 4; mf++)
        af[mf] = *(const s16x8*)&ua[(mf * 16 + lr) * 32 + sl * 8];
      #pragma unroll
      for (int nf = 0; nf < 4; nf++)
        bf[nf] = *(const s16x8*)&ub[(rb + nf * 16) * 32 + sl * 8];
    }
    __builtin_amdgcn_s_setprio(1);
    #pragma unroll
    for (int mf = 0; mf < 4; mf++)
      #pragma unroll
      for (int nf = 0; nf < 4; nf++)
        acc[mf][nf] = __builtin_amdgcn_mfma_f32_16x16x32_bf16(af[mf], bf[nf], acc[mf][nf], 0, 0, 0);
    __builtin_amdgcn_s_setprio(0);
    SBAR();                        // all waves' ds_reads of buf c complete
    if (kt < NT - 2) {
      STAGE(c, (kt + 2) << 5);     // refill c with tile kt+2
      WAITVM5();                   // tile kt+1 resident; kt+2 in flight
    } else if (kt == NT - 2) {
      WAITVM0();                   // last tile resident
    }
    SBAR();
    c ^= 1;
  }
#undef STAGE

  __syncthreads();   // safe LDS reuse as stats
  float bv[4];
  #pragma unroll
  for (int nf = 0; nf < 4; nf++) bv[nf] = bias[wn * 64 + nf * 16 + lr];

  #pragma unroll
  for (int mf = 0; mf < 4; mf++) {
    #pragma unroll
    for (int r = 0; r < 4; r++) {
      int lrow = mf * 16 + lk * 4 + r;
      int grow = m0 + lrow;
      float s = 0.f, q = 0.f;
      #pragma unroll
      for (int nf = 0; nf < 4; nf++) {
        int col = wn * 64 + nf * 16 + lr;
        float v = acc[mf][nf][r] + bv[nf] + bf2f(res[(size_t)grow * 256 + col]);
        acc[mf][nf][r] = v;
        s += v; q += v * v;
      }
      #pragma unroll
      for (int off = 1; off < 16; off <<= 1) { s += __shfl_xor(s, off); q += __shfl_xor(q, off); }
      if (lr == 0) { stats[lrow * 4 + wn] = s; stats[256 + lrow * 4 + wn] = q; }
    }
  }
  __syncthreads();

  float gv[4], bbv[4];
  #pragma unroll
  for (int nf = 0; nf < 4; nf++) {
    int col = wn * 64 + nf * 16 + lr;
    gv[nf] = g[col]; bbv[nf] = bta[col];
  }
  #pragma unroll
  for (int mf = 0; mf < 4; mf++) {
    #pragma unroll
    for (int r = 0; r < 4; r++) {
      int lrow = mf * 16 + lk * 4 + r;
      int grow = m0 + lrow;
      float s4 = stats[lrow * 4 + 0] + stats[lrow * 4 + 1] + stats[lrow * 4 + 2] + stats[lrow * 4 + 3];
      float q4 = stats[256 + lrow * 4 + 0] + stats[256 + lrow * 4 + 1]
               + stats[256 + lrow * 4 + 2] + stats[256 + lrow * 4 + 3];
      float mean = s4 * (1.f / 256.f);
      float var = q4 * (1.f / 256.f) - mean * mean;
      float rs = rsqrtf(var + 1e-5f);
      #pragma unroll
      for (int nf = 0; nf < 4; nf++) {
        int col = wn * 64 + nf * 16 + lr;
        float val = (acc[mf][nf][r] - mean) * rs * gv[nf] + bbv[nf];
        xb[(size_t)grow * 256 + col] = f2bf(val);
        if (WR32) x32[(size_t)grow * 256 + col] = val;
      }
    }
  }
}

// ---------------- attention: one wave per (b,h) ----------------
__global__ __launch_bounds__(64) void attn_kernel(const unsigned short* __restrict__ qkv,
                                                  unsigned short* __restrict__ ob) {
  __shared__ unsigned short qs[64 * 32], ks[64 * 32], vs[64 * 32];
  __shared__ unsigned short ps[64 * 72];
  const int bh = blockIdx.x;
  const int b = bh >> 3, h = bh & 7;
  const int lane = threadIdx.x;
  const int lr = lane & 15, lk = lane >> 4;

  #pragma unroll
  for (int p = 0; p < 4; p++) {
    int u = lane + p * 64;
    int row = u >> 2, seg = u & 3;
    size_t gb = (size_t)(b * 64 + row) * 768 + h * 32 + seg * 8;
    GLOAD_LDS16(qkv + gb, (char*)qs + u * 16);
    GLOAD_LDS16(qkv + gb + 256, (char*)ks + u * 16);
    GLOAD_LDS16(qkv + gb + 512, (char*)vs + u * 16);
  }
  __syncthreads();

  f32x4 s[4][4];
  #pragma unroll
  for (int i = 0; i < 4; i++)
    #pragma unroll
    for (int j = 0; j < 4; j++) s[i][j] = (f32x4)(0.f);
  s16x8 aq[4], bk[4];
  #pragma unroll
  for (int mi = 0; mi < 4; mi++) aq[mi] = *(const s16x8*)&qs[(mi * 16 + lr) * 32 + lk * 8];
  #pragma unroll
  for (int nj = 0; nj < 4; nj++) bk[nj] = *(const s16x8*)&ks[(nj * 16 + lr) * 32 + lk * 8];
  #pragma unroll
  for (int mi = 0; mi < 4; mi++)
    #pragma unroll
    for (int nj = 0; nj < 4; nj++)
      s[mi][nj] = __builtin_amdgcn_mfma_f32_16x16x32_bf16(aq[mi], bk[nj], s[mi][nj], 0, 0, 0);

  const float scale = 0.17677669529663687f;
  #pragma unroll
  for (int mi = 0; mi < 4; mi++) {
    #pragma unroll
    for (int r = 0; r < 4; r++) {
      float t0 = s[mi][0][r] * scale, t1 = s[mi][1][r] * scale;
      float t2 = s[mi][2][r] * scale, t3 = s[mi][3][r] * scale;
      float mx = fmaxf(fmaxf(t0, t1), fmaxf(t2, t3));
      #pragma unroll
      for (int off = 8; off; off >>= 1) mx = fmaxf(mx, __shfl_xor(mx, off, 16));
      float e0 = expf(t0 - mx), e1 = expf(t1 - mx), e2 = expf(t2 - mx), e3 = expf(t3 - mx);
      float sm = e0 + e1 + e2 + e3;
      #pragma unroll
      for (int off = 8; off; off >>= 1) sm += __shfl_xor(sm, off, 16);
      float inv = 1.f / sm;
      int prow = mi * 16 + lk * 4 + r;
      ps[prow * 72 + lr + 0]  = f2bf(e0 * inv);
      ps[prow * 72 + lr + 16] = f2bf(e1 * inv);
      ps[prow * 72 + lr + 32] = f2bf(e2 * inv);
      ps[prow * 72 + lr + 48] = f2bf(e3 * inv);
    }
  }
  __syncthreads();

  f32x4 oacc[4][2];
  #pragma unroll
  for (int i = 0; i < 4; i++) { oacc[i][0] = (f32x4)(0.f); oacc[i][1] = (f32x4)(0.f); }
  #pragma unroll
  for (int kk = 0; kk < 2; kk++) {
    s16x8 bv[2];
    #pragma unroll
    for (int nf = 0; nf < 2; nf++) {
      s16x8 tmp;
      #pragma unroll
      for (int jj = 0; jj < 8; jj++)
        tmp[jj] = (short)vs[(kk * 32 + lk * 8 + jj) * 32 + nf * 16 + lr];
      bv[nf] = tmp;
    }
    #pragma unroll
    for (int mi = 0; mi < 4; mi++) {
      s16x8 ap = *(const s16x8*)&ps[(mi * 16 + lr) * 72 + kk * 32 + lk * 8];
      #pragma unroll
      for (int nf = 0; nf < 2; nf++)
        oacc[mi][nf] = __builtin_amdgcn_mfma_f32_16x16x32_bf16(ap, bv[nf], oacc[mi][nf], 0, 0, 0);
    }
  }
  #pragma unroll
  for (int mi = 0; mi < 4; mi++)
    #pragma unroll
    for (int nf = 0; nf < 2; nf++)
      #pragma unroll
      for (int r = 0; r < 4; r++) {
        int tok = mi * 16 + lk * 4 + r;
        int c = nf * 16 + lr;
        ob[(size_t)(b * 64 + tok) * 256 + h * 32 + c] = f2bf(oacc[mi][nf][r]);
      }
}

// ---------------- cluster probs -> log_emit (LDS-staged mtT) ----------------
__global__ __launch_bounds__(256) void cluster_kernel(const float* __restrict__ x,
                                                      const float* __restrict__ mtT,
                                                      const float* __restrict__ mtn,
                                                      float* __restrict__ log_emit) {
  __shared__ float mts[8192];   // [256 d][32 k]
  __shared__ float es[4][256];
  const int t = threadIdx.x;
  #pragma unroll
  for (int i = 0; i < 8; i++)
    ((float4*)mts)[i * 256 + t] = ((const float4*)mtT)[i * 256 + t];
  const int w = t >> 6, lane = t & 63;
  const int k = lane & 31, half = lane >> 5;
  const float mtnr = mtn[k];
  __syncthreads();
  #pragma unroll 1
  for (int it = 0; it < 8; it++) {
    size_t tok = (size_t)blockIdx.x * 32 + (size_t)w * 8 + it;
    float4 u = *((const float4*)(x + tok * 256) + lane);
    *(float4*)&es[w][lane * 4] = u;
    float e2 = u.x * u.x + u.y * u.y + u.z * u.z + u.w * u.w;
    #pragma unroll
    for (int off = 1; off < 64; off <<= 1) e2 += __shfl_xor(e2, off);
    float acc = 0.f;
    const float* ep = &es[w][half * 128];
    const float* mp = &mts[half * 128 * 32 + k];
    #pragma unroll
    for (int d = 0; d < 128; d += 4) {
      float4 ev = *(const float4*)(ep + d);
      acc += ev.x * mp[(d + 0) * 32] + ev.y * mp[(d + 1) * 32]
           + ev.z * mp[(d + 2) * 32] + ev.w * mp[(d + 3) * 32];
    }
    acc += __shfl_xor(acc, 32);
    float d2 = e2 - 2.f * acc + mtnr;
    float e = expf(-d2 * 0.1f);
    float sm = e;
    #pragma unroll
    for (int off = 16; off; off >>= 1) sm += __shfl_xor(sm, off, 32);
    if (half == 0) log_emit[tok * 32 + k] = logf(e / sm + 1e-10f);
  }
}

// ---------------- HMM forward scan + entropy ----------------
__global__ __launch_bounds__(256) void scan_kernel(const float* __restrict__ log_emit,
                                                   const float* __restrict__ pi,
                                                   const float* __restrict__ A,
                                                   float* __restrict__ cp,
                                                   float* __restrict__ ent) {
  const int g = threadIdx.x >> 5, j = threadIdx.x & 31;
  const int batch = blockIdx.x * 8 + g;
  float regA[32];
  #pragma unroll
  for (int i = 0; i < 32; i++) regA[i] = A[i * 32 + j];
  const float* le = log_emit + (size_t)batch * 64 * 32;
  float* cpo = cp + (size_t)batch * 64 * 32;

  float u = logf(pi[j] + 1e-10f) + le[j];
  float mx = u;
  #pragma unroll
  for (int off = 16; off; off >>= 1) mx = fmaxf(mx, __shfl_xor(mx, off, 32));
  float e = expf(u - mx), sm = e;
  #pragma unroll
  for (int off = 16; off; off >>= 1) sm += __shfl_xor(sm, off, 32);
  float p = e / sm;
  cpo[j] = p;
  float enta = p * logf(p + 1e-10f);

  for (int n = 1; n < 64; n++) {
    float tt = 0.f;
    #pragma unroll
    for (int i = 0; i < 32; i++) tt += __shfl(p, i, 32) * regA[i];
    u = logf(tt + 1e-10f) + le[n * 32 + j];
    mx = u;
    #pragma unroll
    for (int off = 16; off; off >>= 1) mx = fmaxf(mx, __shfl_xor(mx, off, 32));
    e = expf(u - mx); sm = e;
    #pragma unroll
    for (int off = 16; off; off >>= 1) sm += __shfl_xor(sm, off, 32);
    p = e / sm;
    cpo[n * 32 + j] = p;
    enta += p * logf(p + 1e-10f);
  }
  #pragma unroll
  for (int off = 16; off; off >>= 1) enta += __shfl_xor(enta, off, 32);
  if (j == 0) atomicAdd(ent, -enta * (1.f / (2048.f * 64.f)));
}

// ---------------- launcher ----------------
extern "C" void kernel_launch(void* const* d_in, const int* in_sizes, int n_in,
                              void* d_out, int out_size, void* d_ws, size_t ws_size,
                              hipStream_t stream) {
  const float* input = (const float*)d_in[0];
  const float* init_logits = (const float*)d_in[1];
  const float* trans = (const float*)d_in[2];
  const float* Wqkv = (const float*)d_in[3];
  const float* bqkv = (const float*)d_in[4];
  const float* Wo = (const float*)d_in[5];
  const float* bo = (const float*)d_in[6];
  const float* ln1g = (const float*)d_in[7];
  const float* ln1b = (const float*)d_in[8];
  const float* ln2g = (const float*)d_in[9];
  const float* ln2b = (const float*)d_in[10];
  const float* W1 = (const float*)d_in[11];
  const float* b1 = (const float*)d_in[12];
  const float* W2 = (const float*)d_in[13];
  const float* b2 = (const float*)d_in[14];
  const float* mus = (const float*)d_in[15];

  float* out = (float*)d_out;
  float* cp = out;                  // [BN,32]
  float* x = out + 4194304;         // emb_all [BN,256] f32 (written by final gemm_ln)
  float* d_pi = out + 37748736;
  float* d_A = out + 37748768;
  float* d_ent = out + 37749792;

  char* ws = (char*)d_ws;
  unsigned short* qkv = (unsigned short*)ws;        // region A: qkv -> hb -> log_emit
  unsigned short* hb = (unsigned short*)ws;
  float* log_emit = (float*)ws;
  unsigned short* ob = (unsigned short*)(ws + 268435456ull);   // region B
  unsigned short* xb = (unsigned short*)(ws + 335544320ull);   // residual stream bf16
  unsigned short* wq_b = (unsigned short*)(ws + 402653184ull);
  unsigned short* wo_b = (unsigned short*)(ws + 402653184ull + 786432ull);
  unsigned short* w1_b = (unsigned short*)(ws + 402653184ull + 1048576ull);
  unsigned short* w2_b = (unsigned short*)(ws + 402653184ull + 2097152ull);
  float* mtT = (float*)(ws + 402653184ull + 3145728ull);
  float* mtn = (float*)(ws + 402653184ull + 3178496ull);

  cvt_kernel<<<2048, 256, 0, stream>>>((const float4*)input, (ushort4*)xb, BNT * 256 / 4);
  cvt_kernel<<<256, 256, 0, stream>>>((const float4*)Wqkv, (ushort4*)wq_b, LLN * 768 * 256 / 4);
  cvt_kernel<<<256, 256, 0, stream>>>((const float4*)Wo, (ushort4*)wo_b, LLN * 256 * 256 / 4);
  cvt_kernel<<<256, 256, 0, stream>>>((const float4*)W1, (ushort4*)w1_b, LLN * 1024 * 256 / 4);
  cvt_kernel<<<256, 256, 0, stream>>>((const float4*)W2, (ushort4*)w2_b, LLN * 256 * 1024 / 4);
  mt_kernel<<<1, 64, 0, stream>>>(mus, mtT, mtn);
  piA_kernel<<<1, 64, 0, stream>>>(init_logits, trans, d_pi, d_A, d_ent);

  for (int l = 0; l < 2; l++) {
    gemm_nt<0><<<6144, 256, 0, stream>>>(xb, wq_b + l * 196608, bqkv + l * 768,
                                         qkv, 768, 256, 6);
    attn_kernel<<<16384, 64, 0, stream>>>(qkv, ob);
    gemm_ln<false><<<2048, 256, 0, stream>>>(ob, wo_b + l * 65536, bo + l * 256,
                                             xb, ln1g + l * 256, ln1b + l * 256,
                                             xb, nullptr, 256);
    gemm_nt<1><<<8192, 256, 0, stream>>>(xb, w1_b + l * 262144, b1 + l * 1024,
                                         hb, 1024, 256, 8);
    if (l == LLN - 1)
      gemm_ln<true><<<2048, 256, 0, stream>>>(hb, w2_b + l * 262144, b2 + l * 256,
                                              xb, ln2g + l * 256, ln2b + l * 256,
                                              xb, x, 1024);
    else
      gemm_ln<false><<<2048, 256, 0, stream>>>(hb, w2_b + l * 262144, b2 + l * 256,
                                               xb, ln2g + l * 256, ln2b + l * 256,
                                               xb, nullptr, 1024);
  }

  cluster_kernel<<<4096, 256, 0, stream>>>(x, mtT, mtn, log_emit);
  scan_kernel<<<256, 256, 0, stream>>>(log_emit, d_pi, d_A, cp, d_ent);
}

// Round 10
// 1214.896 us; speedup vs baseline: 1.1351x; 1.1351x over previous
//
#include <hip/hip_runtime.h>

#define BB   2048
#define NNX  64
#define DD   256
#define KKC  32
#define LLN  2
#define HHN  8
#define DHH  32
#define DFFN 1024
#define BNT  (BB*NNX)   // 131072

typedef short s16x8 __attribute__((ext_vector_type(8)));
typedef float f32x4 __attribute__((ext_vector_type(4)));

#define GLOAD_LDS16(gp, lp) __builtin_amdgcn_global_load_lds( \
    (const __attribute__((address_space(1))) void*)(gp),      \
    (__attribute__((address_space(3))) void*)(lp), 16, 0, 0)

#define WAITVM4() asm volatile("s_waitcnt vmcnt(4)" ::: "memory")
#define WAITVM0() asm volatile("s_waitcnt vmcnt(0)" ::: "memory")
#define SBAR() __builtin_amdgcn_s_barrier()

__device__ __forceinline__ unsigned short f2bf(float f) {
  unsigned int u = __float_as_uint(f);
  u += 0x7fffu + ((u >> 16) & 1u);   // RNE
  return (unsigned short)(u >> 16);
}
__device__ __forceinline__ float bf2f(unsigned short u) {
  return __uint_as_float(((unsigned int)u) << 16);
}

// ---------------- f32 -> bf16 bulk convert ----------------
__global__ __launch_bounds__(256) void cvt_kernel(const float4* __restrict__ src,
                                                  ushort4* __restrict__ dst, int n4) {
  int i = blockIdx.x * 256 + threadIdx.x;
  int st = gridDim.x * 256;
  for (; i < n4; i += st) {
    float4 v = src[i];
    ushort4 o;
    o.x = f2bf(v.x); o.y = f2bf(v.y); o.z = f2bf(v.z); o.w = f2bf(v.w);
    dst[i] = o;
  }
}

// ---------------- tanh(mu) table (transposed) ----------------
__global__ void mt_kernel(const float* __restrict__ mus, float* __restrict__ mtT,
                          float* __restrict__ mtn) {
  int k = threadIdx.x;
  if (k < 32) {
    float acc = 0.f;
    for (int d = 0; d < 256; d++) {
      float t = tanhf(mus[k * 256 + d]);
      mtT[d * 32 + k] = t;
      acc += t * t;
    }
    mtn[k] = acc;
  }
}

// ---------------- prob_pi, prob_A, zero entropy ----------------
__global__ void piA_kernel(const float* __restrict__ il, const float* __restrict__ tl,
                           float* __restrict__ d_pi, float* __restrict__ d_A,
                           float* __restrict__ d_ent) {
  int lane = threadIdx.x;
  if (lane == 0) *d_ent = 0.f;
  if (lane < 32) {
    float v = il[lane];
    float mx = v;
    #pragma unroll
    for (int off = 16; off; off >>= 1) mx = fmaxf(mx, __shfl_xor(mx, off, 32));
    float e = expf(v - mx), sm = e;
    #pragma unroll
    for (int off = 16; off; off >>= 1) sm += __shfl_xor(sm, off, 32);
    d_pi[lane] = e / sm;
    for (int r = 0; r < 32; r++) {
      float a = tl[r * 32 + lane];
      float m2 = a;
      #pragma unroll
      for (int off = 16; off; off >>= 1) m2 = fmaxf(m2, __shfl_xor(m2, off, 32));
      float e2 = expf(a - m2), s2 = e2;
      #pragma unroll
      for (int off = 16; off; off >>= 1) s2 += __shfl_xor(s2, off, 32);
      d_A[r * 32 + lane] = e2 / s2;
    }
  }
}

// ======== 128x128 tile, BK=32, 4-wave, counted-vmcnt pipelined NT GEMM ========
// (R7-proven, unchanged) EPI 0: bf16 out; 1: relu->bf16.
template <int EPI>
__global__ __launch_bounds__(256, 4) void gemm_nt(const unsigned short* __restrict__ A,
                                                  const unsigned short* __restrict__ Bw,
                                                  const float* __restrict__ bias,
                                                  unsigned short* __restrict__ outp,
                                                  int N, int K, int nx) {
  __shared__ unsigned short lds[16384];   // 32 KB: [2 buf][A 4096 | B 4096]
  const int t = threadIdx.x;
  const int bid = blockIdx.x, nwg = gridDim.x;
  const int wg = (bid & 7) * (nwg >> 3) + (bid >> 3);   // nwg % 8 == 0
  const int m0 = (wg / nx) << 7;
  const int n0 = (wg % nx) << 7;
  const int lane = t & 63, w = t >> 6;
  const int wm = w >> 1, wn = w & 1;      // 2x2 waves, wave tile 64x64
  const int lr = lane & 15, lk = lane >> 4;

  const int r0 = t >> 2, sg = t & 3;
  const int s0 = sg ^ ((r0 >> 1) & 3);
  const int r1 = r0 + 64;
  const int s1 = sg ^ ((r1 >> 1) & 3);
  const int aoff0 = (m0 + r0) * K + s0 * 8;
  const int aoff1 = (m0 + r1) * K + s1 * 8;
  const int boff0 = (n0 + r0) * K + s0 * 8;
  const int boff1 = (n0 + r1) * K + s1 * 8;

#define STAGE(buf, k0) do {                                    \
    char* la = (char*)lds + (buf) * 16384;                     \
    GLOAD_LDS16(A + aoff0 + (k0), la + t * 16);                \
    GLOAD_LDS16(A + aoff1 + (k0), la + 4096 + t * 16);         \
    GLOAD_LDS16(Bw + boff0 + (k0), la + 8192 + t * 16);        \
    GLOAD_LDS16(Bw + boff1 + (k0), la + 12288 + t * 16);       \
  } while (0)

  f32x4 acc[4][4];
  #pragma unroll
  for (int i = 0; i < 4; i++)
    #pragma unroll
    for (int j = 0; j < 4; j++) acc[i][j] = (f32x4)(0.f);

  const int ra = wm * 64 + lr, rb = wn * 64 + lr;
  const int sla = lk ^ ((ra >> 1) & 3), slb = lk ^ ((rb >> 1) & 3);

  const int NT = K >> 5;
  STAGE(0, 0);
  STAGE(1, 32);
  WAITVM4();
  SBAR();

  int c = 0;
  for (int kt = 0; kt < NT; kt++) {
    s16x8 af[4], bf[4];
    {
      const unsigned short* ua = lds + c * 8192;
      const unsigned short* ub = ua + 4096;
      #pragma unroll
      for (int mf = 0; mf < 4; mf++)
        af[mf] = *(const s16x8*)&ua[(ra + mf * 16) * 32 + sla * 8];
      #pragma unroll
      for (int nf = 0; nf < 4; nf++)
        bf[nf] = *(const s16x8*)&ub[(rb + nf * 16) * 32 + slb * 8];
    }
    __builtin_amdgcn_s_setprio(1);
    #pragma unroll
    for (int mf = 0; mf < 4; mf++)
      #pragma unroll
      for (int nf = 0; nf < 4; nf++)
        acc[mf][nf] = __builtin_amdgcn_mfma_f32_16x16x32_bf16(af[mf], bf[nf], acc[mf][nf], 0, 0, 0);
    __builtin_amdgcn_s_setprio(0);
    SBAR();
    if (kt < NT - 2) {
      STAGE(c, (kt + 2) << 5);
      WAITVM4();
    } else if (kt == NT - 2) {
      WAITVM0();
    }
    SBAR();
    c ^= 1;
  }
#undef STAGE

  #pragma unroll
  for (int nf = 0; nf < 4; nf++) {
    int col = n0 + wn * 64 + nf * 16 + lr;
    float bv = bias[col];
    #pragma unroll
    for (int mf = 0; mf < 4; mf++)
      #pragma unroll
      for (int r = 0; r < 4; r++) {
        int row = m0 + wm * 64 + mf * 16 + lk * 4 + r;
        float v = acc[mf][nf][r] + bv;
        if (EPI == 1) v = fmaxf(v, 0.f);
        outp[(size_t)row * N + col] = f2bf(v);
      }
  }
}

// ------- GEMM (BM=128, BN=256 full width) + bias + residual + LayerNorm -------
// (R4-measured version, verbatim: 151 us FFN2 / ~55 us Wo)
template <bool WR32>
__global__ __launch_bounds__(512) void gemm_ln(const unsigned short* __restrict__ A,
                                               const unsigned short* __restrict__ Bw,
                                               const float* __restrict__ bias,
                                               const unsigned short* __restrict__ res,
                                               const float* __restrict__ g,
                                               const float* __restrict__ bta,
                                               unsigned short* __restrict__ xb,
                                               float* __restrict__ x32,
                                               int K) {
  __shared__ unsigned short As[128 * 64];
  __shared__ unsigned short Bs[256 * 64];
  __shared__ float stats[2][128][4];
  const int t = threadIdx.x;
  const int nwg = gridDim.x;
  const int bid = blockIdx.x;
  const int wg = (bid & 7) * (nwg >> 3) + (bid >> 3);
  const int m0 = wg << 7;

  const int lane = t & 63, w = t >> 6;
  const int wm = w >> 2, wn = w & 3;
  const int lr = lane & 15, lk = lane >> 4;

  size_t aoff[2], boff[4];
  #pragma unroll
  for (int p = 0; p < 2; p++) {
    int u = p * 512 + t;
    int row = u >> 3, sp = u & 7;
    int seg = sp ^ (((row >> 2) & 1) << 1);
    aoff[p] = (size_t)(m0 + row) * K + seg * 8;
  }
  #pragma unroll
  for (int p = 0; p < 4; p++) {
    int u = p * 512 + t;
    int row = u >> 3, sp = u & 7;
    int seg = sp ^ (((row >> 2) & 1) << 1);
    boff[p] = (size_t)row * K + seg * 8;
  }

  f32x4 acc[4][4];
  #pragma unroll
  for (int i = 0; i < 4; i++)
    #pragma unroll
    for (int j = 0; j < 4; j++) acc[i][j] = (f32x4)(0.f);

  for (int k0 = 0; k0 < K; k0 += 64) {
    #pragma unroll
    for (int p = 0; p < 2; p++)
      GLOAD_LDS16(A + aoff[p] + k0, (char*)As + (p * 512 + t) * 16);
    #pragma unroll
    for (int p = 0; p < 4; p++)
      GLOAD_LDS16(Bw + boff[p] + k0, (char*)Bs + (p * 512 + t) * 16);
    __syncthreads();
    #pragma unroll
    for (int z = 0; z < 2; z++) {
      s16x8 af[4], bfr[4];
      #pragma unroll
      for (int mf = 0; mf < 4; mf++) {
        int row = wm * 64 + mf * 16 + lr;
        int cc = (z * 4 + lk) ^ (((row >> 2) & 1) << 1);
        af[mf] = *(const s16x8*)&As[row * 64 + cc * 8];
      }
      #pragma unroll
      for (int nf = 0; nf < 4; nf++) {
        int row = wn * 64 + nf * 16 + lr;
        int cc = (z * 4 + lk) ^ (((row >> 2) & 1) << 1);
        bfr[nf] = *(const s16x8*)&Bs[row * 64 + cc * 8];
      }
      #pragma unroll
      for (int mf = 0; mf < 4; mf++)
        #pragma unroll
        for (int nf = 0; nf < 4; nf++)
          acc[mf][nf] = __builtin_amdgcn_mfma_f32_16x16x32_bf16(af[mf], bfr[nf], acc[mf][nf], 0, 0, 0);
    }
    __syncthreads();
  }

  float bv[4];
  #pragma unroll
  for (int nf = 0; nf < 4; nf++) bv[nf] = bias[wn * 64 + nf * 16 + lr];

  #pragma unroll
  for (int mf = 0; mf < 4; mf++) {
    #pragma unroll
    for (int r = 0; r < 4; r++) {
      int grow = m0 + wm * 64 + mf * 16 + lk * 4 + r;
      float s = 0.f, q = 0.f;
      #pragma unroll
      for (int nf = 0; nf < 4; nf++) {
        int col = wn * 64 + nf * 16 + lr;
        float v = acc[mf][nf][r] + bv[nf] + bf2f(res[(size_t)grow * 256 + col]);
        acc[mf][nf][r] = v;
        s += v; q += v * v;
      }
      #pragma unroll
      for (int off = 1; off < 16; off <<= 1) { s += __shfl_xor(s, off); q += __shfl_xor(q, off); }
      if (lr == 0) {
        int lrow = wm * 64 + mf * 16 + lk * 4 + r;
        stats[0][lrow][wn] = s;
        stats[1][lrow][wn] = q;
      }
    }
  }
  __syncthreads();

  float gv[4], bbv[4];
  #pragma unroll
  for (int nf = 0; nf < 4; nf++) {
    int col = wn * 64 + nf * 16 + lr;
    gv[nf] = g[col]; bbv[nf] = bta[col];
  }
  #pragma unroll
  for (int mf = 0; mf < 4; mf++) {
    #pragma unroll
    for (int r = 0; r < 4; r++) {
      int lrow = wm * 64 + mf * 16 + lk * 4 + r;
      int grow = m0 + lrow;
      float s4 = stats[0][lrow][0] + stats[0][lrow][1] + stats[0][lrow][2] + stats[0][lrow][3];
      float q4 = stats[1][lrow][0] + stats[1][lrow][1] + stats[1][lrow][2] + stats[1][lrow][3];
      float mean = s4 * (1.f / 256.f);
      float var = q4 * (1.f / 256.f) - mean * mean;
      float rs = rsqrtf(var + 1e-5f);
      #pragma unroll
      for (int nf = 0; nf < 4; nf++) {
        int col = wn * 64 + nf * 16 + lr;
        float val = (acc[mf][nf][r] - mean) * rs * gv[nf] + bbv[nf];
        xb[(size_t)grow * 256 + col] = f2bf(val);
        if (WR32) x32[(size_t)grow * 256 + col] = val;
      }
    }
  }
}

// ---------------- attention: one wave per (b,h), compact LDS ----------------
// ps[64][72] aliases the q/k staging region (Q/K fragments are consumed into
// registers before softmax writes P; value deps order the LDS ops). LDS
// 21.5 KB -> 13.3 KB => 12 blocks/CU instead of 7.
__global__ __launch_bounds__(64) void attn_kernel(const unsigned short* __restrict__ qkv,
                                                  unsigned short* __restrict__ ob) {
  __shared__ unsigned short al[6656];   // 13312 B
  unsigned short* qs = al;              // [64][32] @ bytes [0, 4096)
  unsigned short* ks = al + 2048;       // [64][32] @ bytes [4096, 8192)
  unsigned short* ps = al;              // [64][72] @ bytes [0, 9216) -- aliases qs+ks
  unsigned short* vs = al + 4608;       // [64][32] @ bytes [9216, 13312)
  const int bh = blockIdx.x;
  const int b = bh >> 3, h = bh & 7;
  const int lane = threadIdx.x;
  const int lr = lane & 15, lk = lane >> 4;

  #pragma unroll
  for (int p = 0; p < 4; p++) {
    int u = lane + p * 64;
    int row = u >> 2, seg = u & 3;
    size_t gb = (size_t)(b * 64 + row) * 768 + h * 32 + seg * 8;
    GLOAD_LDS16(qkv + gb, (char*)al + u * 16);
    GLOAD_LDS16(qkv + gb + 256, (char*)al + 4096 + u * 16);
    GLOAD_LDS16(qkv + gb + 512, (char*)al + 9216 + u * 16);
  }
  __syncthreads();

  f32x4 s[4][4];
  #pragma unroll
  for (int i = 0; i < 4; i++)
    #pragma unroll
    for (int j = 0; j < 4; j++) s[i][j] = (f32x4)(0.f);
  s16x8 aq[4], bk[4];
  #pragma unroll
  for (int mi = 0; mi < 4; mi++) aq[mi] = *(const s16x8*)&qs[(mi * 16 + lr) * 32 + lk * 8];
  #pragma unroll
  for (int nj = 0; nj < 4; nj++) bk[nj] = *(const s16x8*)&ks[(nj * 16 + lr) * 32 + lk * 8];
  #pragma unroll
  for (int mi = 0; mi < 4; mi++)
    #pragma unroll
    for (int nj = 0; nj < 4; nj++)
      s[mi][nj] = __builtin_amdgcn_mfma_f32_16x16x32_bf16(aq[mi], bk[nj], s[mi][nj], 0, 0, 0);

  const float scale = 0.17677669529663687f;
  #pragma unroll
  for (int mi = 0; mi < 4; mi++) {
    #pragma unroll
    for (int r = 0; r < 4; r++) {
      float t0 = s[mi][0][r] * scale, t1 = s[mi][1][r] * scale;
      float t2 = s[mi][2][r] * scale, t3 = s[mi][3][r] * scale;
      float mx = fmaxf(fmaxf(t0, t1), fmaxf(t2, t3));
      #pragma unroll
      for (int off = 8; off; off >>= 1) mx = fmaxf(mx, __shfl_xor(mx, off, 16));
      float e0 = expf(t0 - mx), e1 = expf(t1 - mx), e2 = expf(t2 - mx), e3 = expf(t3 - mx);
      float sm = e0 + e1 + e2 + e3;
      #pragma unroll
      for (int off = 8; off; off >>= 1) sm += __shfl_xor(sm, off, 16);
      float inv = 1.f / sm;
      int prow = mi * 16 + lk * 4 + r;
      ps[prow * 72 + lr + 0]  = f2bf(e0 * inv);
      ps[prow * 72 + lr + 16] = f2bf(e1 * inv);
      ps[prow * 72 + lr + 32] = f2bf(e2 * inv);
      ps[prow * 72 + lr + 48] = f2bf(e3 * inv);
    }
  }
  __syncthreads();

  f32x4 oacc[4][2];
  #pragma unroll
  for (int i = 0; i < 4; i++) { oacc[i][0] = (f32x4)(0.f); oacc[i][1] = (f32x4)(0.f); }
  #pragma unroll
  for (int kk = 0; kk < 2; kk++) {
    s16x8 bv[2];
    #pragma unroll
    for (int nf = 0; nf < 2; nf++) {
      s16x8 tmp;
      #pragma unroll
      for (int jj = 0; jj < 8; jj++)
        tmp[jj] = (short)vs[(kk * 32 + lk * 8 + jj) * 32 + nf * 16 + lr];
      bv[nf] = tmp;
    }
    #pragma unroll
    for (int mi = 0; mi < 4; mi++) {
      s16x8 ap = *(const s16x8*)&ps[(mi * 16 + lr) * 72 + kk * 32 + lk * 8];
      #pragma unroll
      for (int nf = 0; nf < 2; nf++)
        oacc[mi][nf] = __builtin_amdgcn_mfma_f32_16x16x32_bf16(ap, bv[nf], oacc[mi][nf], 0, 0, 0);
    }
  }
  #pragma unroll
  for (int mi = 0; mi < 4; mi++)
    #pragma unroll
    for (int nf = 0; nf < 2; nf++)
      #pragma unroll
      for (int r = 0; r < 4; r++) {
        int tok = mi * 16 + lk * 4 + r;
        int c = nf * 16 + lr;
        ob[(size_t)(b * 64 + tok) * 256 + h * 32 + c] = f2bf(oacc[mi][nf][r]);
      }
}

// ---------------- cluster probs -> log_emit (LDS-staged mtT) ----------------
__global__ __launch_bounds__(256) void cluster_kernel(const float* __restrict__ x,
                                                      const float* __restrict__ mtT,
                                                      const float* __restrict__ mtn,
                                                      float* __restrict__ log_emit) {
  __shared__ float mts[8192];   // [256 d][32 k]
  __shared__ float es[4][256];
  const int t = threadIdx.x;
  #pragma unroll
  for (int i = 0; i < 8; i++)
    ((float4*)mts)[i * 256 + t] = ((const float4*)mtT)[i * 256 + t];
  const int w = t >> 6, lane = t & 63;
  const int k = lane & 31, half = lane >> 5;
  const float mtnr = mtn[k];
  __syncthreads();
  #pragma unroll 1
  for (int it = 0; it < 8; it++) {
    size_t tok = (size_t)blockIdx.x * 32 + (size_t)w * 8 + it;
    float4 u = *((const float4*)(x + tok * 256) + lane);
    *(float4*)&es[w][lane * 4] = u;
    float e2 = u.x * u.x + u.y * u.y + u.z * u.z + u.w * u.w;
    #pragma unroll
    for (int off = 1; off < 64; off <<= 1) e2 += __shfl_xor(e2, off);
    float acc = 0.f;
    const float* ep = &es[w][half * 128];
    const float* mp = &mts[half * 128 * 32 + k];
    #pragma unroll
    for (int d = 0; d < 128; d += 4) {
      float4 ev = *(const float4*)(ep + d);
      acc += ev.x * mp[(d + 0) * 32] + ev.y * mp[(d + 1) * 32]
           + ev.z * mp[(d + 2) * 32] + ev.w * mp[(d + 3) * 32];
    }
    acc += __shfl_xor(acc, 32);
    float d2 = e2 - 2.f * acc + mtnr;
    float e = expf(-d2 * 0.1f);
    float sm = e;
    #pragma unroll
    for (int off = 16; off; off >>= 1) sm += __shfl_xor(sm, off, 32);
    if (half == 0) log_emit[tok * 32 + k] = logf(e / sm + 1e-10f);
  }
}

// ---------------- HMM forward scan + entropy ----------------
__global__ __launch_bounds__(256) void scan_kernel(const float* __restrict__ log_emit,
                                                   const float* __restrict__ pi,
                                                   const float* __restrict__ A,
                                                   float* __restrict__ cp,
                                                   float* __restrict__ ent) {
  const int g = threadIdx.x >> 5, j = threadIdx.x & 31;
  const int batch = blockIdx.x * 8 + g;
  float regA[32];
  #pragma unroll
  for (int i = 0; i < 32; i++) regA[i] = A[i * 32 + j];
  const float* le = log_emit + (size_t)batch * 64 * 32;
  float* cpo = cp + (size_t)batch * 64 * 32;

  float u = logf(pi[j] + 1e-10f) + le[j];
  float mx = u;
  #pragma unroll
  for (int off = 16; off; off >>= 1) mx = fmaxf(mx, __shfl_xor(mx, off, 32));
  float e = expf(u - mx), sm = e;
  #pragma unroll
  for (int off = 16; off; off >>= 1) sm += __shfl_xor(sm, off, 32);
  float p = e / sm;
  cpo[j] = p;
  float enta = p * logf(p + 1e-10f);

  for (int n = 1; n < 64; n++) {
    float tt = 0.f;
    #pragma unroll
    for (int i = 0; i < 32; i++) tt += __shfl(p, i, 32) * regA[i];
    u = logf(tt + 1e-10f) + le[n * 32 + j];
    mx = u;
    #pragma unroll
    for (int off = 16; off; off >>= 1) mx = fmaxf(mx, __shfl_xor(mx, off, 32));
    e = expf(u - mx); sm = e;
    #pragma unroll
    for (int off = 16; off; off >>= 1) sm += __shfl_xor(sm, off, 32);
    p = e / sm;
    cpo[n * 32 + j] = p;
    enta += p * logf(p + 1e-10f);
  }
  #pragma unroll
  for (int off = 16; off; off >>= 1) enta += __shfl_xor(enta, off, 32);
  if (j == 0) atomicAdd(ent, -enta * (1.f / (2048.f * 64.f)));
}

// ---------------- launcher ----------------
extern "C" void kernel_launch(void* const* d_in, const int* in_sizes, int n_in,
                              void* d_out, int out_size, void* d_ws, size_t ws_size,
                              hipStream_t stream) {
  const float* input = (const float*)d_in[0];
  const float* init_logits = (const float*)d_in[1];
  const float* trans = (const float*)d_in[2];
  const float* Wqkv = (const float*)d_in[3];
  const float* bqkv = (const float*)d_in[4];
  const float* Wo = (const float*)d_in[5];
  const float* bo = (const float*)d_in[6];
  const float* ln1g = (const float*)d_in[7];
  const float* ln1b = (const float*)d_in[8];
  const float* ln2g = (const float*)d_in[9];
  const float* ln2b = (const float*)d_in[10];
  const float* W1 = (const float*)d_in[11];
  const float* b1 = (const float*)d_in[12];
  const float* W2 = (const float*)d_in[13];
  const float* b2 = (const float*)d_in[14];
  const float* mus = (const float*)d_in[15];

  float* out = (float*)d_out;
  float* cp = out;                  // [BN,32]
  float* x = out + 4194304;         // emb_all [BN,256] f32 (written by final gemm_ln)
  float* d_pi = out + 37748736;
  float* d_A = out + 37748768;
  float* d_ent = out + 37749792;

  char* ws = (char*)d_ws;
  unsigned short* qkv = (unsigned short*)ws;        // region A: qkv -> hb -> log_emit
  unsigned short* hb = (unsigned short*)ws;
  float* log_emit = (float*)ws;
  unsigned short* ob = (unsigned short*)(ws + 268435456ull);   // region B
  unsigned short* xb = (unsigned short*)(ws + 335544320ull);   // residual stream bf16
  unsigned short* wq_b = (unsigned short*)(ws + 402653184ull);
  unsigned short* wo_b = (unsigned short*)(ws + 402653184ull + 786432ull);
  unsigned short* w1_b = (unsigned short*)(ws + 402653184ull + 1048576ull);
  unsigned short* w2_b = (unsigned short*)(ws + 402653184ull + 2097152ull);
  float* mtT = (float*)(ws + 402653184ull + 3145728ull);
  float* mtn = (float*)(ws + 402653184ull + 3178496ull);

  cvt_kernel<<<2048, 256, 0, stream>>>((const float4*)input, (ushort4*)xb, BNT * 256 / 4);
  cvt_kernel<<<256, 256, 0, stream>>>((const float4*)Wqkv, (ushort4*)wq_b, LLN * 768 * 256 / 4);
  cvt_kernel<<<256, 256, 0, stream>>>((const float4*)Wo, (ushort4*)wo_b, LLN * 256 * 256 / 4);
  cvt_kernel<<<256, 256, 0, stream>>>((const float4*)W1, (ushort4*)w1_b, LLN * 1024 * 256 / 4);
  cvt_kernel<<<256, 256, 0, stream>>>((const float4*)W2, (ushort4*)w2_b, LLN * 256 * 1024 / 4);
  mt_kernel<<<1, 64, 0, stream>>>(mus, mtT, mtn);
  piA_kernel<<<1, 64, 0, stream>>>(init_logits, trans, d_pi, d_A, d_ent);

  for (int l = 0; l < 2; l++) {
    gemm_nt<0><<<6144, 256, 0, stream>>>(xb, wq_b + l * 196608, bqkv + l * 768,
                                         qkv, 768, 256, 6);
    attn_kernel<<<16384, 64, 0, stream>>>(qkv, ob);
    gemm_ln<false><<<1024, 512, 0, stream>>>(ob, wo_b + l * 65536, bo + l * 256,
                                             xb, ln1g + l * 256, ln1b + l * 256,
                                             xb, nullptr, 256);
    gemm_nt<1><<<8192, 256, 0, stream>>>(xb, w1_b + l * 262144, b1 + l * 1024,
                                         hb, 1024, 256, 8);
    if (l == LLN - 1)
      gemm_ln<true><<<1024, 512, 0, stream>>>(hb, w2_b + l * 262144, b2 + l * 256,
                                              xb, ln2g + l * 256, ln2b + l * 256,
                                              xb, x, 1024);
    else
      gemm_ln<false><<<1024, 512, 0, stream>>>(hb, w2_b + l * 262144, b2 + l * 256,
                                               xb, ln2g + l * 256, ln2b + l * 256,
                                               xb, nullptr, 1024);
  }

  cluster_kernel<<<4096, 256, 0, stream>>>(x, mtT, mtn, log_emit);
  scan_kernel<<<256, 256, 0, stream>>>(log_emit, d_pi, d_A, cp, d_ent);
}

// Round 11
// 1191.562 us; speedup vs baseline: 1.1573x; 1.0196x over previous
//
#include <hip/hip_runtime.h>

#define BB   2048
#define NNX  64
#define DD   256
#define KKC  32
#define LLN  2
#define HHN  8
#define DHH  32
#define DFFN 1024
#define BNT  (BB*NNX)   // 131072

typedef short s16x8 __attribute__((ext_vector_type(8)));
typedef float f32x4 __attribute__((ext_vector_type(4)));

#define GLOAD_LDS16(gp, lp) __builtin_amdgcn_global_load_lds( \
    (const __attribute__((address_space(1))) void*)(gp),      \
    (__attribute__((address_space(3))) void*)(lp), 16, 0, 0)

#define WAITVM4() asm volatile("s_waitcnt vmcnt(4)" ::: "memory")
#define WAITVM0() asm volatile("s_waitcnt vmcnt(0)" ::: "memory")
#define WAITLGKM0() do { asm volatile("s_waitcnt lgkmcnt(0)" ::: "memory"); \
                         __builtin_amdgcn_sched_barrier(0); } while (0)
#define SBAR() __builtin_amdgcn_s_barrier()

__device__ __forceinline__ unsigned short f2bf(float f) {
  unsigned int u = __float_as_uint(f);
  u += 0x7fffu + ((u >> 16) & 1u);   // RNE
  return (unsigned short)(u >> 16);
}
__device__ __forceinline__ float bf2f(unsigned short u) {
  return __uint_as_float(((unsigned int)u) << 16);
}

// ---------------- f32 -> bf16 bulk convert (input) ----------------
__global__ __launch_bounds__(256) void cvt_kernel(const float4* __restrict__ src,
                                                  ushort4* __restrict__ dst, int n4) {
  int i = blockIdx.x * 256 + threadIdx.x;
  int st = gridDim.x * 256;
  for (; i < n4; i += st) {
    float4 v = src[i];
    ushort4 o;
    o.x = f2bf(v.x); o.y = f2bf(v.y); o.z = f2bf(v.z); o.w = f2bf(v.w);
    dst[i] = o;
  }
}

// ---------------- all-weights f32 -> bf16 in one launch ----------------
__global__ __launch_bounds__(256) void cvtw_kernel(const float4* __restrict__ wq, ushort4* __restrict__ dq,
                                                   const float4* __restrict__ wo, ushort4* __restrict__ dov,
                                                   const float4* __restrict__ w1, ushort4* __restrict__ d1,
                                                   const float4* __restrict__ w2, ushort4* __restrict__ d2) {
  const int n0 = 98304, n1 = 32768, n2 = 131072, n3 = 131072;  // float4 counts
  int i = blockIdx.x * 256 + threadIdx.x;
  int st = gridDim.x * 256;
  for (; i < n0 + n1 + n2 + n3; i += st) {
    const float4* s; ushort4* d; int j = i;
    if (j < n0) { s = wq; d = dq; }
    else if ((j -= n0) < n1) { s = wo; d = dov; }
    else if ((j -= n1) < n2) { s = w1; d = d1; }
    else { j -= n2; s = w2; d = d2; }
    float4 v = s[j];
    ushort4 o;
    o.x = f2bf(v.x); o.y = f2bf(v.y); o.z = f2bf(v.z); o.w = f2bf(v.w);
    d[j] = o;
  }
}

// ---------------- tanh(mu) table (transposed) ----------------
__global__ void mt_kernel(const float* __restrict__ mus, float* __restrict__ mtT,
                          float* __restrict__ mtn) {
  int k = threadIdx.x;
  if (k < 32) {
    float acc = 0.f;
    for (int d = 0; d < 256; d++) {
      float t = tanhf(mus[k * 256 + d]);
      mtT[d * 32 + k] = t;
      acc += t * t;
    }
    mtn[k] = acc;
  }
}

// ---------------- prob_pi, prob_A, zero entropy ----------------
__global__ void piA_kernel(const float* __restrict__ il, const float* __restrict__ tl,
                           float* __restrict__ d_pi, float* __restrict__ d_A,
                           float* __restrict__ d_ent) {
  int lane = threadIdx.x;
  if (lane == 0) *d_ent = 0.f;
  if (lane < 32) {
    float v = il[lane];
    float mx = v;
    #pragma unroll
    for (int off = 16; off; off >>= 1) mx = fmaxf(mx, __shfl_xor(mx, off, 32));
    float e = expf(v - mx), sm = e;
    #pragma unroll
    for (int off = 16; off; off >>= 1) sm += __shfl_xor(sm, off, 32);
    d_pi[lane] = e / sm;
    for (int r = 0; r < 32; r++) {
      float a = tl[r * 32 + lane];
      float m2 = a;
      #pragma unroll
      for (int off = 16; off; off >>= 1) m2 = fmaxf(m2, __shfl_xor(m2, off, 32));
      float e2 = expf(a - m2), s2 = e2;
      #pragma unroll
      for (int off = 16; off; off >>= 1) s2 += __shfl_xor(s2, off, 32);
      d_A[r * 32 + lane] = e2 / s2;
    }
  }
}

// ======== 128x128 tile, BK=32, 4-wave, counted-vmcnt pipelined NT GEMM ========
// (R7-proven, unchanged) EPI 0: bf16 out; 1: relu->bf16.
template <int EPI>
__global__ __launch_bounds__(256, 4) void gemm_nt(const unsigned short* __restrict__ A,
                                                  const unsigned short* __restrict__ Bw,
                                                  const float* __restrict__ bias,
                                                  unsigned short* __restrict__ outp,
                                                  int N, int K, int nx) {
  __shared__ unsigned short lds[16384];   // 32 KB: [2 buf][A 4096 | B 4096]
  const int t = threadIdx.x;
  const int bid = blockIdx.x, nwg = gridDim.x;
  const int wg = (bid & 7) * (nwg >> 3) + (bid >> 3);   // nwg % 8 == 0
  const int m0 = (wg / nx) << 7;
  const int n0 = (wg % nx) << 7;
  const int lane = t & 63, w = t >> 6;
  const int wm = w >> 1, wn = w & 1;      // 2x2 waves, wave tile 64x64
  const int lr = lane & 15, lk = lane >> 4;

  const int r0 = t >> 2, sg = t & 3;
  const int s0 = sg ^ ((r0 >> 1) & 3);
  const int r1 = r0 + 64;
  const int s1 = sg ^ ((r1 >> 1) & 3);
  const int aoff0 = (m0 + r0) * K + s0 * 8;
  const int aoff1 = (m0 + r1) * K + s1 * 8;
  const int boff0 = (n0 + r0) * K + s0 * 8;
  const int boff1 = (n0 + r1) * K + s1 * 8;

#define STAGE(buf, k0) do {                                    \
    char* la = (char*)lds + (buf) * 16384;                     \
    GLOAD_LDS16(A + aoff0 + (k0), la + t * 16);                \
    GLOAD_LDS16(A + aoff1 + (k0), la + 4096 + t * 16);         \
    GLOAD_LDS16(Bw + boff0 + (k0), la + 8192 + t * 16);        \
    GLOAD_LDS16(Bw + boff1 + (k0), la + 12288 + t * 16);       \
  } while (0)

  f32x4 acc[4][4];
  #pragma unroll
  for (int i = 0; i < 4; i++)
    #pragma unroll
    for (int j = 0; j < 4; j++) acc[i][j] = (f32x4)(0.f);

  const int ra = wm * 64 + lr, rb = wn * 64 + lr;
  const int sla = lk ^ ((ra >> 1) & 3), slb = lk ^ ((rb >> 1) & 3);

  const int NT = K >> 5;
  STAGE(0, 0);
  STAGE(1, 32);
  WAITVM4();
  SBAR();

  int c = 0;
  for (int kt = 0; kt < NT; kt++) {
    s16x8 af[4], bf[4];
    {
      const unsigned short* ua = lds + c * 8192;
      const unsigned short* ub = ua + 4096;
      #pragma unroll
      for (int mf = 0; mf < 4; mf++)
        af[mf] = *(const s16x8*)&ua[(ra + mf * 16) * 32 + sla * 8];
      #pragma unroll
      for (int nf = 0; nf < 4; nf++)
        bf[nf] = *(const s16x8*)&ub[(rb + nf * 16) * 32 + slb * 8];
    }
    __builtin_amdgcn_s_setprio(1);
    #pragma unroll
    for (int mf = 0; mf < 4; mf++)
      #pragma unroll
      for (int nf = 0; nf < 4; nf++)
        acc[mf][nf] = __builtin_amdgcn_mfma_f32_16x16x32_bf16(af[mf], bf[nf], acc[mf][nf], 0, 0, 0);
    __builtin_amdgcn_s_setprio(0);
    SBAR();
    if (kt < NT - 2) {
      STAGE(c, (kt + 2) << 5);
      WAITVM4();
    } else if (kt == NT - 2) {
      WAITVM0();
    }
    SBAR();
    c ^= 1;
  }
#undef STAGE

  #pragma unroll
  for (int nf = 0; nf < 4; nf++) {
    int col = n0 + wn * 64 + nf * 16 + lr;
    float bv = bias[col];
    #pragma unroll
    for (int mf = 0; mf < 4; mf++)
      #pragma unroll
      for (int r = 0; r < 4; r++) {
        int row = m0 + wm * 64 + mf * 16 + lk * 4 + r;
        float v = acc[mf][nf][r] + bv;
        if (EPI == 1) v = fmaxf(v, 0.f);
        outp[(size_t)row * N + col] = f2bf(v);
      }
  }
}

// ------- GEMM (BM=128, BN=256 full width) + bias + residual + LayerNorm -------
// (R4-measured version, verbatim)
template <bool WR32>
__global__ __launch_bounds__(512) void gemm_ln(const unsigned short* __restrict__ A,
                                               const unsigned short* __restrict__ Bw,
                                               const float* __restrict__ bias,
                                               const unsigned short* __restrict__ res,
                                               const float* __restrict__ g,
                                               const float* __restrict__ bta,
                                               unsigned short* __restrict__ xb,
                                               float* __restrict__ x32,
                                               int K) {
  __shared__ unsigned short As[128 * 64];
  __shared__ unsigned short Bs[256 * 64];
  __shared__ float stats[2][128][4];
  const int t = threadIdx.x;
  const int nwg = gridDim.x;
  const int bid = blockIdx.x;
  const int wg = (bid & 7) * (nwg >> 3) + (bid >> 3);
  const int m0 = wg << 7;

  const int lane = t & 63, w = t >> 6;
  const int wm = w >> 2, wn = w & 3;
  const int lr = lane & 15, lk = lane >> 4;

  size_t aoff[2], boff[4];
  #pragma unroll
  for (int p = 0; p < 2; p++) {
    int u = p * 512 + t;
    int row = u >> 3, sp = u & 7;
    int seg = sp ^ (((row >> 2) & 1) << 1);
    aoff[p] = (size_t)(m0 + row) * K + seg * 8;
  }
  #pragma unroll
  for (int p = 0; p < 4; p++) {
    int u = p * 512 + t;
    int row = u >> 3, sp = u & 7;
    int seg = sp ^ (((row >> 2) & 1) << 1);
    boff[p] = (size_t)row * K + seg * 8;
  }

  f32x4 acc[4][4];
  #pragma unroll
  for (int i = 0; i < 4; i++)
    #pragma unroll
    for (int j = 0; j < 4; j++) acc[i][j] = (f32x4)(0.f);

  for (int k0 = 0; k0 < K; k0 += 64) {
    #pragma unroll
    for (int p = 0; p < 2; p++)
      GLOAD_LDS16(A + aoff[p] + k0, (char*)As + (p * 512 + t) * 16);
    #pragma unroll
    for (int p = 0; p < 4; p++)
      GLOAD_LDS16(Bw + boff[p] + k0, (char*)Bs + (p * 512 + t) * 16);
    __syncthreads();
    #pragma unroll
    for (int z = 0; z < 2; z++) {
      s16x8 af[4], bfr[4];
      #pragma unroll
      for (int mf = 0; mf < 4; mf++) {
        int row = wm * 64 + mf * 16 + lr;
        int cc = (z * 4 + lk) ^ (((row >> 2) & 1) << 1);
        af[mf] = *(const s16x8*)&As[row * 64 + cc * 8];
      }
      #pragma unroll
      for (int nf = 0; nf < 4; nf++) {
        int row = wn * 64 + nf * 16 + lr;
        int cc = (z * 4 + lk) ^ (((row >> 2) & 1) << 1);
        bfr[nf] = *(const s16x8*)&Bs[row * 64 + cc * 8];
      }
      #pragma unroll
      for (int mf = 0; mf < 4; mf++)
        #pragma unroll
        for (int nf = 0; nf < 4; nf++)
          acc[mf][nf] = __builtin_amdgcn_mfma_f32_16x16x32_bf16(af[mf], bfr[nf], acc[mf][nf], 0, 0, 0);
    }
    __syncthreads();
  }

  float bv[4];
  #pragma unroll
  for (int nf = 0; nf < 4; nf++) bv[nf] = bias[wn * 64 + nf * 16 + lr];

  #pragma unroll
  for (int mf = 0; mf < 4; mf++) {
    #pragma unroll
    for (int r = 0; r < 4; r++) {
      int grow = m0 + wm * 64 + mf * 16 + lk * 4 + r;
      float s = 0.f, q = 0.f;
      #pragma unroll
      for (int nf = 0; nf < 4; nf++) {
        int col = wn * 64 + nf * 16 + lr;
        float v = acc[mf][nf][r] + bv[nf] + bf2f(res[(size_t)grow * 256 + col]);
        acc[mf][nf][r] = v;
        s += v; q += v * v;
      }
      #pragma unroll
      for (int off = 1; off < 16; off <<= 1) { s += __shfl_xor(s, off); q += __shfl_xor(q, off); }
      if (lr == 0) {
        int lrow = wm * 64 + mf * 16 + lk * 4 + r;
        stats[0][lrow][wn] = s;
        stats[1][lrow][wn] = q;
      }
    }
  }
  __syncthreads();

  float gv[4], bbv[4];
  #pragma unroll
  for (int nf = 0; nf < 4; nf++) {
    int col = wn * 64 + nf * 16 + lr;
    gv[nf] = g[col]; bbv[nf] = bta[col];
  }
  #pragma unroll
  for (int mf = 0; mf < 4; mf++) {
    #pragma unroll
    for (int r = 0; r < 4; r++) {
      int lrow = wm * 64 + mf * 16 + lk * 4 + r;
      int grow = m0 + lrow;
      float s4 = stats[0][lrow][0] + stats[0][lrow][1] + stats[0][lrow][2] + stats[0][lrow][3];
      float q4 = stats[1][lrow][0] + stats[1][lrow][1] + stats[1][lrow][2] + stats[1][lrow][3];
      float mean = s4 * (1.f / 256.f);
      float var = q4 * (1.f / 256.f) - mean * mean;
      float rs = rsqrtf(var + 1e-5f);
      #pragma unroll
      for (int nf = 0; nf < 4; nf++) {
        int col = wn * 64 + nf * 16 + lr;
        float val = (acc[mf][nf][r] - mean) * rs * gv[nf] + bbv[nf];
        xb[(size_t)grow * 256 + col] = f2bf(val);
        if (WR32) x32[(size_t)grow * 256 + col] = val;
      }
    }
  }
}

// ---------------- attention: one wave per (b,h), compact LDS, V^T ----------
// LDS byte map (13568 B, 11 blocks/CU):
//   stage:  qs@[0,4096)  ks@[4096,8192)  vs@[9216,13312)
//   post:   vt@[0,4352)  (32 cols x 68-short stride; aliases qs+ks head)
//           ps@[4352,13568) (64 x 72-short rows; aliases ks tail + vs)
// Single-wave block: explicit lgkmcnt(0)+sched_barrier fences order the
// aliased reads/writes (rule #18). PV B-frags become vector b128 reads of
// vt instead of 64 scalar ds_read_u16.
__global__ __launch_bounds__(64) void attn_kernel(const unsigned short* __restrict__ qkv,
                                                  unsigned short* __restrict__ ob) {
  __shared__ unsigned short al[6784];   // 13568 B
  unsigned short* qs = al;              // shorts [0,2048)
  unsigned short* ks = al + 2048;       // shorts [2048,4096)
  unsigned short* vs = al + 4608;       // shorts [4608,6656)
  unsigned short* vt = al;              // shorts [0,2176)   = [32][68]
  unsigned short* ps = al + 2176;       // shorts [2176,6784) = [64][72]
  const int bh = blockIdx.x;
  const int b = bh >> 3, h = bh & 7;
  const int lane = threadIdx.x;
  const int lr = lane & 15, lk = lane >> 4;

  #pragma unroll
  for (int p = 0; p < 4; p++) {
    int u = lane + p * 64;
    int row = u >> 2, seg = u & 3;
    size_t gb = (size_t)(b * 64 + row) * 768 + h * 32 + seg * 8;
    GLOAD_LDS16(qkv + gb, (char*)al + u * 16);
    GLOAD_LDS16(qkv + gb + 256, (char*)al + 4096 + u * 16);
    GLOAD_LDS16(qkv + gb + 512, (char*)al + 9216 + u * 16);
  }
  __syncthreads();

  // 1) Q/K fragments + V row-chunks into registers
  s16x8 aq[4], bk[4], vchunk[4];
  #pragma unroll
  for (int mi = 0; mi < 4; mi++) aq[mi] = *(const s16x8*)&qs[(mi * 16 + lr) * 32 + lk * 8];
  #pragma unroll
  for (int nj = 0; nj < 4; nj++) bk[nj] = *(const s16x8*)&ks[(nj * 16 + lr) * 32 + lk * 8];
  const int vrow = lane >> 2, vcs = (lane & 3) * 8;
  #pragma unroll
  for (int q = 0; q < 4; q++)
    vchunk[q] = *(const s16x8*)&vs[(q * 16 + vrow) * 32 + vcs];
  WAITLGKM0();   // all aliased-region reads complete before overwrites

  // 2) build vt[c][k] = V[k][c]
  #pragma unroll
  for (int q = 0; q < 4; q++)
    #pragma unroll
    for (int j = 0; j < 8; j++)
      vt[(vcs + j) * 68 + q * 16 + vrow] = (unsigned short)vchunk[q][j];

  // 3) QK^T
  f32x4 s[4][4];
  #pragma unroll
  for (int i = 0; i < 4; i++)
    #pragma unroll
    for (int j = 0; j < 4; j++) s[i][j] = (f32x4)(0.f);
  #pragma unroll
  for (int mi = 0; mi < 4; mi++)
    #pragma unroll
    for (int nj = 0; nj < 4; nj++)
      s[mi][nj] = __builtin_amdgcn_mfma_f32_16x16x32_bf16(aq[mi], bk[nj], s[mi][nj], 0, 0, 0);

  // 4) softmax -> ps
  const float scale = 0.17677669529663687f;
  #pragma unroll
  for (int mi = 0; mi < 4; mi++) {
    #pragma unroll
    for (int r = 0; r < 4; r++) {
      float t0 = s[mi][0][r] * scale, t1 = s[mi][1][r] * scale;
      float t2 = s[mi][2][r] * scale, t3 = s[mi][3][r] * scale;
      float mx = fmaxf(fmaxf(t0, t1), fmaxf(t2, t3));
      #pragma unroll
      for (int off = 8; off; off >>= 1) mx = fmaxf(mx, __shfl_xor(mx, off, 16));
      float e0 = expf(t0 - mx), e1 = expf(t1 - mx), e2 = expf(t2 - mx), e3 = expf(t3 - mx);
      float sm = e0 + e1 + e2 + e3;
      #pragma unroll
      for (int off = 8; off; off >>= 1) sm += __shfl_xor(sm, off, 16);
      float inv = 1.f / sm;
      int prow = mi * 16 + lk * 4 + r;
      ps[prow * 72 + lr + 0]  = f2bf(e0 * inv);
      ps[prow * 72 + lr + 16] = f2bf(e1 * inv);
      ps[prow * 72 + lr + 32] = f2bf(e2 * inv);
      ps[prow * 72 + lr + 48] = f2bf(e3 * inv);
    }
  }
  WAITLGKM0();   // vt + ps writes landed before PV reads

  // 5) PV with vector B-frags from vt
  f32x4 oacc[4][2];
  #pragma unroll
  for (int i = 0; i < 4; i++) { oacc[i][0] = (f32x4)(0.f); oacc[i][1] = (f32x4)(0.f); }
  #pragma unroll
  for (int kk = 0; kk < 2; kk++) {
    s16x8 bv[2];
    #pragma unroll
    for (int nf = 0; nf < 2; nf++)
      bv[nf] = *(const s16x8*)&vt[(nf * 16 + lr) * 68 + kk * 32 + lk * 8];
    #pragma unroll
    for (int mi = 0; mi < 4; mi++) {
      s16x8 ap = *(const s16x8*)&ps[(mi * 16 + lr) * 72 + kk * 32 + lk * 8];
      #pragma unroll
      for (int nf = 0; nf < 2; nf++)
        oacc[mi][nf] = __builtin_amdgcn_mfma_f32_16x16x32_bf16(ap, bv[nf], oacc[mi][nf], 0, 0, 0);
    }
  }
  #pragma unroll
  for (int mi = 0; mi < 4; mi++)
    #pragma unroll
    for (int nf = 0; nf < 2; nf++)
      #pragma unroll
      for (int r = 0; r < 4; r++) {
        int tok = mi * 16 + lk * 4 + r;
        int c = nf * 16 + lr;
        ob[(size_t)(b * 64 + tok) * 256 + h * 32 + c] = f2bf(oacc[mi][nf][r]);
      }
}

// ---------------- cluster probs -> log_emit (bf16 x, LDS-staged mtT) --------
__global__ __launch_bounds__(256) void cluster_kernel(const unsigned short* __restrict__ xb,
                                                      const float* __restrict__ mtT,
                                                      const float* __restrict__ mtn,
                                                      float* __restrict__ log_emit) {
  __shared__ float mts[8192];   // [256 d][32 k]
  __shared__ float es[4][256];
  const int t = threadIdx.x;
  #pragma unroll
  for (int i = 0; i < 8; i++)
    ((float4*)mts)[i * 256 + t] = ((const float4*)mtT)[i * 256 + t];
  const int w = t >> 6, lane = t & 63;
  const int k = lane & 31, half = lane >> 5;
  const float mtnr = mtn[k];
  __syncthreads();
  #pragma unroll 1
  for (int it = 0; it < 8; it++) {
    size_t tok = (size_t)blockIdx.x * 32 + (size_t)w * 8 + it;
    ushort4 u = *((const ushort4*)(xb + tok * 256) + lane);
    float v0 = bf2f(u.x), v1 = bf2f(u.y), v2 = bf2f(u.z), v3 = bf2f(u.w);
    float4 fv = {v0, v1, v2, v3};
    *(float4*)&es[w][lane * 4] = fv;
    float e2 = v0 * v0 + v1 * v1 + v2 * v2 + v3 * v3;
    #pragma unroll
    for (int off = 1; off < 64; off <<= 1) e2 += __shfl_xor(e2, off);
    float acc = 0.f;
    const float* ep = &es[w][half * 128];
    const float* mp = &mts[half * 128 * 32 + k];
    #pragma unroll
    for (int d = 0; d < 128; d += 4) {
      float4 ev = *(const float4*)(ep + d);
      acc += ev.x * mp[(d + 0) * 32] + ev.y * mp[(d + 1) * 32]
           + ev.z * mp[(d + 2) * 32] + ev.w * mp[(d + 3) * 32];
    }
    acc += __shfl_xor(acc, 32);
    float d2 = e2 - 2.f * acc + mtnr;
    float e = expf(-d2 * 0.1f);
    float sm = e;
    #pragma unroll
    for (int off = 16; off; off >>= 1) sm += __shfl_xor(sm, off, 32);
    if (half == 0) log_emit[tok * 32 + k] = logf(e / sm + 1e-10f);
  }
}

// ---------------- HMM forward scan + entropy ----------------
__global__ __launch_bounds__(256) void scan_kernel(const float* __restrict__ log_emit,
                                                   const float* __restrict__ pi,
                                                   const float* __restrict__ A,
                                                   float* __restrict__ cp,
                                                   float* __restrict__ ent) {
  const int g = threadIdx.x >> 5, j = threadIdx.x & 31;
  const int batch = blockIdx.x * 8 + g;
  float regA[32];
  #pragma unroll
  for (int i = 0; i < 32; i++) regA[i] = A[i * 32 + j];
  const float* le = log_emit + (size_t)batch * 64 * 32;
  float* cpo = cp + (size_t)batch * 64 * 32;

  float u = logf(pi[j] + 1e-10f) + le[j];
  float mx = u;
  #pragma unroll
  for (int off = 16; off; off >>= 1) mx = fmaxf(mx, __shfl_xor(mx, off, 32));
  float e = expf(u - mx), sm = e;
  #pragma unroll
  for (int off = 16; off; off >>= 1) sm += __shfl_xor(sm, off, 32);
  float p = e / sm;
  cpo[j] = p;
  float enta = p * logf(p + 1e-10f);

  for (int n = 1; n < 64; n++) {
    float tt = 0.f;
    #pragma unroll
    for (int i = 0; i < 32; i++) tt += __shfl(p, i, 32) * regA[i];
    u = logf(tt + 1e-10f) + le[n * 32 + j];
    mx = u;
    #pragma unroll
    for (int off = 16; off; off >>= 1) mx = fmaxf(mx, __shfl_xor(mx, off, 32));
    e = expf(u - mx); sm = e;
    #pragma unroll
    for (int off = 16; off; off >>= 1) sm += __shfl_xor(sm, off, 32);
    p = e / sm;
    cpo[n * 32 + j] = p;
    enta += p * logf(p + 1e-10f);
  }
  #pragma unroll
  for (int off = 16; off; off >>= 1) enta += __shfl_xor(enta, off, 32);
  if (j == 0) atomicAdd(ent, -enta * (1.f / (2048.f * 64.f)));
}

// ---------------- launcher ----------------
extern "C" void kernel_launch(void* const* d_in, const int* in_sizes, int n_in,
                              void* d_out, int out_size, void* d_ws, size_t ws_size,
                              hipStream_t stream) {
  const float* input = (const float*)d_in[0];
  const float* init_logits = (const float*)d_in[1];
  const float* trans = (const float*)d_in[2];
  const float* Wqkv = (const float*)d_in[3];
  const float* bqkv = (const float*)d_in[4];
  const float* Wo = (const float*)d_in[5];
  const float* bo = (const float*)d_in[6];
  const float* ln1g = (const float*)d_in[7];
  const float* ln1b = (const float*)d_in[8];
  const float* ln2g = (const float*)d_in[9];
  const float* ln2b = (const float*)d_in[10];
  const float* W1 = (const float*)d_in[11];
  const float* b1 = (const float*)d_in[12];
  const float* W2 = (const float*)d_in[13];
  const float* b2 = (const float*)d_in[14];
  const float* mus = (const float*)d_in[15];

  float* out = (float*)d_out;
  float* cp = out;                  // [BN,32]
  float* x = out + 4194304;         // emb_all [BN,256] f32 (written by final gemm_ln)
  float* d_pi = out + 37748736;
  float* d_A = out + 37748768;
  float* d_ent = out + 37749792;

  char* ws = (char*)d_ws;
  unsigned short* qkv = (unsigned short*)ws;        // region A: qkv -> hb -> log_emit
  unsigned short* hb = (unsigned short*)ws;
  float* log_emit = (float*)ws;
  unsigned short* ob = (unsigned short*)(ws + 268435456ull);   // region B
  unsigned short* xb = (unsigned short*)(ws + 335544320ull);   // residual stream bf16
  unsigned short* wq_b = (unsigned short*)(ws + 402653184ull);
  unsigned short* wo_b = (unsigned short*)(ws + 402653184ull + 786432ull);
  unsigned short* w1_b = (unsigned short*)(ws + 402653184ull + 1048576ull);
  unsigned short* w2_b = (unsigned short*)(ws + 402653184ull + 2097152ull);
  float* mtT = (float*)(ws + 402653184ull + 3145728ull);
  float* mtn = (float*)(ws + 402653184ull + 3178496ull);

  cvt_kernel<<<2048, 256, 0, stream>>>((const float4*)input, (ushort4*)xb, BNT * 256 / 4);
  cvtw_kernel<<<512, 256, 0, stream>>>((const float4*)Wqkv, (ushort4*)wq_b,
                                       (const float4*)Wo, (ushort4*)wo_b,
                                       (const float4*)W1, (ushort4*)w1_b,
                                       (const float4*)W2, (ushort4*)w2_b);
  mt_kernel<<<1, 64, 0, stream>>>(mus, mtT, mtn);
  piA_kernel<<<1, 64, 0, stream>>>(init_logits, trans, d_pi, d_A, d_ent);

  for (int l = 0; l < 2; l++) {
    gemm_nt<0><<<6144, 256, 0, stream>>>(xb, wq_b + l * 196608, bqkv + l * 768,
                                         qkv, 768, 256, 6);
    attn_kernel<<<16384, 64, 0, stream>>>(qkv, ob);
    gemm_ln<false><<<1024, 512, 0, stream>>>(ob, wo_b + l * 65536, bo + l * 256,
                                             xb, ln1g + l * 256, ln1b + l * 256,
                                             xb, nullptr, 256);
    gemm_nt<1><<<8192, 256, 0, stream>>>(xb, w1_b + l * 262144, b1 + l * 1024,
                                         hb, 1024, 256, 8);
    if (l == LLN - 1)
      gemm_ln<true><<<1024, 512, 0, stream>>>(hb, w2_b + l * 262144, b2 + l * 256,
                                              xb, ln2g + l * 256, ln2b + l * 256,
                                              xb, x, 1024);
    else
      gemm_ln<false><<<1024, 512, 0, stream>>>(hb, w2_b + l * 262144, b2 + l * 256,
                                               xb, ln2g + l * 256, ln2b + l * 256,
                                               xb, nullptr, 1024);
  }

  cluster_kernel<<<4096, 256, 0, stream>>>(xb, mtT, mtn, log_emit);
  scan_kernel<<<256, 256, 0, stream>>>(log_emit, d_pi, d_A, cp, d_ent);
}

// Round 12
// 1141.462 us; speedup vs baseline: 1.2081x; 1.0439x over previous
//
#include <hip/hip_runtime.h>

#define BB   2048
#define NNX  64
#define DD   256
#define KKC  32
#define LLN  2
#define HHN  8
#define DHH  32
#define DFFN 1024
#define BNT  (BB*NNX)   // 131072

typedef short s16x8 __attribute__((ext_vector_type(8)));
typedef float f32x4 __attribute__((ext_vector_type(4)));

#define GLOAD_LDS16(gp, lp) __builtin_amdgcn_global_load_lds( \
    (const __attribute__((address_space(1))) void*)(gp),      \
    (__attribute__((address_space(3))) void*)(lp), 16, 0, 0)

#define WAITVM4() asm volatile("s_waitcnt vmcnt(4)" ::: "memory")
#define WAITVM0() asm volatile("s_waitcnt vmcnt(0)" ::: "memory")
#define WAITLGKM0() do { asm volatile("s_waitcnt lgkmcnt(0)" ::: "memory"); \
                         __builtin_amdgcn_sched_barrier(0); } while (0)
#define SBAR() __builtin_amdgcn_s_barrier()

__device__ __forceinline__ unsigned short f2bf(float f) {
  unsigned int u = __float_as_uint(f);
  u += 0x7fffu + ((u >> 16) & 1u);   // RNE
  return (unsigned short)(u >> 16);
}
__device__ __forceinline__ float bf2f(unsigned short u) {
  return __uint_as_float(((unsigned int)u) << 16);
}

// ---------------- f32 -> bf16 bulk convert (input) ----------------
__global__ __launch_bounds__(256) void cvt_kernel(const float4* __restrict__ src,
                                                  ushort4* __restrict__ dst, int n4) {
  int i = blockIdx.x * 256 + threadIdx.x;
  int st = gridDim.x * 256;
  for (; i < n4; i += st) {
    float4 v = src[i];
    ushort4 o;
    o.x = f2bf(v.x); o.y = f2bf(v.y); o.z = f2bf(v.z); o.w = f2bf(v.w);
    dst[i] = o;
  }
}

// ---------------- all-weights f32 -> bf16 in one launch ----------------
__global__ __launch_bounds__(256) void cvtw_kernel(const float4* __restrict__ wq, ushort4* __restrict__ dq,
                                                   const float4* __restrict__ wo, ushort4* __restrict__ dov,
                                                   const float4* __restrict__ w1, ushort4* __restrict__ d1,
                                                   const float4* __restrict__ w2, ushort4* __restrict__ d2) {
  const int n0 = 98304, n1 = 32768, n2 = 131072, n3 = 131072;  // float4 counts
  int i = blockIdx.x * 256 + threadIdx.x;
  int st = gridDim.x * 256;
  for (; i < n0 + n1 + n2 + n3; i += st) {
    const float4* s; ushort4* d; int j = i;
    if (j < n0) { s = wq; d = dq; }
    else if ((j -= n0) < n1) { s = wo; d = dov; }
    else if ((j -= n1) < n2) { s = w1; d = d1; }
    else { j -= n2; s = w2; d = d2; }
    float4 v = s[j];
    ushort4 o;
    o.x = f2bf(v.x); o.y = f2bf(v.y); o.z = f2bf(v.z); o.w = f2bf(v.w);
    d[j] = o;
  }
}

// -------- tanh(mu) table: bf16 [32][264] (padded) + |mt|^2 f32 --------
__global__ void mt_kernel(const float* __restrict__ mus, unsigned short* __restrict__ mtb,
                          float* __restrict__ mtn) {
  int k = threadIdx.x;
  if (k < 32) {
    float acc = 0.f;
    for (int d = 0; d < 256; d++) {
      float t = tanhf(mus[k * 256 + d]);
      mtb[k * 264 + d] = f2bf(t);
      acc += t * t;
    }
    mtn[k] = acc;
  }
}

// ---------------- prob_pi, prob_A, zero entropy ----------------
__global__ void piA_kernel(const float* __restrict__ il, const float* __restrict__ tl,
                           float* __restrict__ d_pi, float* __restrict__ d_A,
                           float* __restrict__ d_ent) {
  int lane = threadIdx.x;
  if (lane == 0) *d_ent = 0.f;
  if (lane < 32) {
    float v = il[lane];
    float mx = v;
    #pragma unroll
    for (int off = 16; off; off >>= 1) mx = fmaxf(mx, __shfl_xor(mx, off, 32));
    float e = expf(v - mx), sm = e;
    #pragma unroll
    for (int off = 16; off; off >>= 1) sm += __shfl_xor(sm, off, 32);
    d_pi[lane] = e / sm;
    for (int r = 0; r < 32; r++) {
      float a = tl[r * 32 + lane];
      float m2 = a;
      #pragma unroll
      for (int off = 16; off; off >>= 1) m2 = fmaxf(m2, __shfl_xor(m2, off, 32));
      float e2 = expf(a - m2), s2 = e2;
      #pragma unroll
      for (int off = 16; off; off >>= 1) s2 += __shfl_xor(s2, off, 32);
      d_A[r * 32 + lane] = e2 / s2;
    }
  }
}

// ======== 128x128 tile, BK=32, 4-wave, counted-vmcnt pipelined NT GEMM ========
// (R7-proven, unchanged) EPI 0: bf16 out; 1: relu->bf16.
template <int EPI>
__global__ __launch_bounds__(256, 4) void gemm_nt(const unsigned short* __restrict__ A,
                                                  const unsigned short* __restrict__ Bw,
                                                  const float* __restrict__ bias,
                                                  unsigned short* __restrict__ outp,
                                                  int N, int K, int nx) {
  __shared__ unsigned short lds[16384];   // 32 KB: [2 buf][A 4096 | B 4096]
  const int t = threadIdx.x;
  const int bid = blockIdx.x, nwg = gridDim.x;
  const int wg = (bid & 7) * (nwg >> 3) + (bid >> 3);   // nwg % 8 == 0
  const int m0 = (wg / nx) << 7;
  const int n0 = (wg % nx) << 7;
  const int lane = t & 63, w = t >> 6;
  const int wm = w >> 1, wn = w & 1;      // 2x2 waves, wave tile 64x64
  const int lr = lane & 15, lk = lane >> 4;

  const int r0 = t >> 2, sg = t & 3;
  const int s0 = sg ^ ((r0 >> 1) & 3);
  const int r1 = r0 + 64;
  const int s1 = sg ^ ((r1 >> 1) & 3);
  const int aoff0 = (m0 + r0) * K + s0 * 8;
  const int aoff1 = (m0 + r1) * K + s1 * 8;
  const int boff0 = (n0 + r0) * K + s0 * 8;
  const int boff1 = (n0 + r1) * K + s1 * 8;

#define STAGE(buf, k0) do {                                    \
    char* la = (char*)lds + (buf) * 16384;                     \
    GLOAD_LDS16(A + aoff0 + (k0), la + t * 16);                \
    GLOAD_LDS16(A + aoff1 + (k0), la + 4096 + t * 16);         \
    GLOAD_LDS16(Bw + boff0 + (k0), la + 8192 + t * 16);        \
    GLOAD_LDS16(Bw + boff1 + (k0), la + 12288 + t * 16);       \
  } while (0)

  f32x4 acc[4][4];
  #pragma unroll
  for (int i = 0; i < 4; i++)
    #pragma unroll
    for (int j = 0; j < 4; j++) acc[i][j] = (f32x4)(0.f);

  const int ra = wm * 64 + lr, rb = wn * 64 + lr;
  const int sla = lk ^ ((ra >> 1) & 3), slb = lk ^ ((rb >> 1) & 3);

  const int NT = K >> 5;
  STAGE(0, 0);
  STAGE(1, 32);
  WAITVM4();
  SBAR();

  int c = 0;
  for (int kt = 0; kt < NT; kt++) {
    s16x8 af[4], bf[4];
    {
      const unsigned short* ua = lds + c * 8192;
      const unsigned short* ub = ua + 4096;
      #pragma unroll
      for (int mf = 0; mf < 4; mf++)
        af[mf] = *(const s16x8*)&ua[(ra + mf * 16) * 32 + sla * 8];
      #pragma unroll
      for (int nf = 0; nf < 4; nf++)
        bf[nf] = *(const s16x8*)&ub[(rb + nf * 16) * 32 + slb * 8];
    }
    __builtin_amdgcn_s_setprio(1);
    #pragma unroll
    for (int mf = 0; mf < 4; mf++)
      #pragma unroll
      for (int nf = 0; nf < 4; nf++)
        acc[mf][nf] = __builtin_amdgcn_mfma_f32_16x16x32_bf16(af[mf], bf[nf], acc[mf][nf], 0, 0, 0);
    __builtin_amdgcn_s_setprio(0);
    SBAR();
    if (kt < NT - 2) {
      STAGE(c, (kt + 2) << 5);
      WAITVM4();
    } else if (kt == NT - 2) {
      WAITVM0();
    }
    SBAR();
    c ^= 1;
  }
#undef STAGE

  #pragma unroll
  for (int nf = 0; nf < 4; nf++) {
    int col = n0 + wn * 64 + nf * 16 + lr;
    float bv = bias[col];
    #pragma unroll
    for (int mf = 0; mf < 4; mf++)
      #pragma unroll
      for (int r = 0; r < 4; r++) {
        int row = m0 + wm * 64 + mf * 16 + lk * 4 + r;
        float v = acc[mf][nf][r] + bv;
        if (EPI == 1) v = fmaxf(v, 0.f);
        outp[(size_t)row * N + col] = f2bf(v);
      }
  }
}

// ------- GEMM (BM=128, BN=256 full width) + bias + residual + LayerNorm -------
// (R4-measured version, verbatim)
template <bool WR32>
__global__ __launch_bounds__(512) void gemm_ln(const unsigned short* __restrict__ A,
                                               const unsigned short* __restrict__ Bw,
                                               const float* __restrict__ bias,
                                               const unsigned short* __restrict__ res,
                                               const float* __restrict__ g,
                                               const float* __restrict__ bta,
                                               unsigned short* __restrict__ xb,
                                               float* __restrict__ x32,
                                               int K) {
  __shared__ unsigned short As[128 * 64];
  __shared__ unsigned short Bs[256 * 64];
  __shared__ float stats[2][128][4];
  const int t = threadIdx.x;
  const int nwg = gridDim.x;
  const int bid = blockIdx.x;
  const int wg = (bid & 7) * (nwg >> 3) + (bid >> 3);
  const int m0 = wg << 7;

  const int lane = t & 63, w = t >> 6;
  const int wm = w >> 2, wn = w & 3;
  const int lr = lane & 15, lk = lane >> 4;

  size_t aoff[2], boff[4];
  #pragma unroll
  for (int p = 0; p < 2; p++) {
    int u = p * 512 + t;
    int row = u >> 3, sp = u & 7;
    int seg = sp ^ (((row >> 2) & 1) << 1);
    aoff[p] = (size_t)(m0 + row) * K + seg * 8;
  }
  #pragma unroll
  for (int p = 0; p < 4; p++) {
    int u = p * 512 + t;
    int row = u >> 3, sp = u & 7;
    int seg = sp ^ (((row >> 2) & 1) << 1);
    boff[p] = (size_t)row * K + seg * 8;
  }

  f32x4 acc[4][4];
  #pragma unroll
  for (int i = 0; i < 4; i++)
    #pragma unroll
    for (int j = 0; j < 4; j++) acc[i][j] = (f32x4)(0.f);

  for (int k0 = 0; k0 < K; k0 += 64) {
    #pragma unroll
    for (int p = 0; p < 2; p++)
      GLOAD_LDS16(A + aoff[p] + k0, (char*)As + (p * 512 + t) * 16);
    #pragma unroll
    for (int p = 0; p < 4; p++)
      GLOAD_LDS16(Bw + boff[p] + k0, (char*)Bs + (p * 512 + t) * 16);
    __syncthreads();
    #pragma unroll
    for (int z = 0; z < 2; z++) {
      s16x8 af[4], bfr[4];
      #pragma unroll
      for (int mf = 0; mf < 4; mf++) {
        int row = wm * 64 + mf * 16 + lr;
        int cc = (z * 4 + lk) ^ (((row >> 2) & 1) << 1);
        af[mf] = *(const s16x8*)&As[row * 64 + cc * 8];
      }
      #pragma unroll
      for (int nf = 0; nf < 4; nf++) {
        int row = wn * 64 + nf * 16 + lr;
        int cc = (z * 4 + lk) ^ (((row >> 2) & 1) << 1);
        bfr[nf] = *(const s16x8*)&Bs[row * 64 + cc * 8];
      }
      #pragma unroll
      for (int mf = 0; mf < 4; mf++)
        #pragma unroll
        for (int nf = 0; nf < 4; nf++)
          acc[mf][nf] = __builtin_amdgcn_mfma_f32_16x16x32_bf16(af[mf], bfr[nf], acc[mf][nf], 0, 0, 0);
    }
    __syncthreads();
  }

  float bv[4];
  #pragma unroll
  for (int nf = 0; nf < 4; nf++) bv[nf] = bias[wn * 64 + nf * 16 + lr];

  #pragma unroll
  for (int mf = 0; mf < 4; mf++) {
    #pragma unroll
    for (int r = 0; r < 4; r++) {
      int grow = m0 + wm * 64 + mf * 16 + lk * 4 + r;
      float s = 0.f, q = 0.f;
      #pragma unroll
      for (int nf = 0; nf < 4; nf++) {
        int col = wn * 64 + nf * 16 + lr;
        float v = acc[mf][nf][r] + bv[nf] + bf2f(res[(size_t)grow * 256 + col]);
        acc[mf][nf][r] = v;
        s += v; q += v * v;
      }
      #pragma unroll
      for (int off = 1; off < 16; off <<= 1) { s += __shfl_xor(s, off); q += __shfl_xor(q, off); }
      if (lr == 0) {
        int lrow = wm * 64 + mf * 16 + lk * 4 + r;
        stats[0][lrow][wn] = s;
        stats[1][lrow][wn] = q;
      }
    }
  }
  __syncthreads();

  float gv[4], bbv[4];
  #pragma unroll
  for (int nf = 0; nf < 4; nf++) {
    int col = wn * 64 + nf * 16 + lr;
    gv[nf] = g[col]; bbv[nf] = bta[col];
  }
  #pragma unroll
  for (int mf = 0; mf < 4; mf++) {
    #pragma unroll
    for (int r = 0; r < 4; r++) {
      int lrow = wm * 64 + mf * 16 + lk * 4 + r;
      int grow = m0 + lrow;
      float s4 = stats[0][lrow][0] + stats[0][lrow][1] + stats[0][lrow][2] + stats[0][lrow][3];
      float q4 = stats[1][lrow][0] + stats[1][lrow][1] + stats[1][lrow][2] + stats[1][lrow][3];
      float mean = s4 * (1.f / 256.f);
      float var = q4 * (1.f / 256.f) - mean * mean;
      float rs = rsqrtf(var + 1e-5f);
      #pragma unroll
      for (int nf = 0; nf < 4; nf++) {
        int col = wn * 64 + nf * 16 + lr;
        float val = (acc[mf][nf][r] - mean) * rs * gv[nf] + bbv[nf];
        xb[(size_t)grow * 256 + col] = f2bf(val);
        if (WR32) x32[(size_t)grow * 256 + col] = val;
      }
    }
  }
}

// ---------------- attention: one wave per (b,h), compact LDS, V^T ----------
// (R11-proven, unchanged)
__global__ __launch_bounds__(64) void attn_kernel(const unsigned short* __restrict__ qkv,
                                                  unsigned short* __restrict__ ob) {
  __shared__ unsigned short al[6784];   // 13568 B
  unsigned short* qs = al;              // shorts [0,2048)
  unsigned short* ks = al + 2048;       // shorts [2048,4096)
  unsigned short* vs = al + 4608;       // shorts [4608,6656)
  unsigned short* vt = al;              // shorts [0,2176)   = [32][68]
  unsigned short* ps = al + 2176;       // shorts [2176,6784) = [64][72]
  const int bh = blockIdx.x;
  const int b = bh >> 3, h = bh & 7;
  const int lane = threadIdx.x;
  const int lr = lane & 15, lk = lane >> 4;

  #pragma unroll
  for (int p = 0; p < 4; p++) {
    int u = lane + p * 64;
    int row = u >> 2, seg = u & 3;
    size_t gb = (size_t)(b * 64 + row) * 768 + h * 32 + seg * 8;
    GLOAD_LDS16(qkv + gb, (char*)al + u * 16);
    GLOAD_LDS16(qkv + gb + 256, (char*)al + 4096 + u * 16);
    GLOAD_LDS16(qkv + gb + 512, (char*)al + 9216 + u * 16);
  }
  __syncthreads();

  s16x8 aq[4], bk[4], vchunk[4];
  #pragma unroll
  for (int mi = 0; mi < 4; mi++) aq[mi] = *(const s16x8*)&qs[(mi * 16 + lr) * 32 + lk * 8];
  #pragma unroll
  for (int nj = 0; nj < 4; nj++) bk[nj] = *(const s16x8*)&ks[(nj * 16 + lr) * 32 + lk * 8];
  const int vrow = lane >> 2, vcs = (lane & 3) * 8;
  #pragma unroll
  for (int q = 0; q < 4; q++)
    vchunk[q] = *(const s16x8*)&vs[(q * 16 + vrow) * 32 + vcs];
  WAITLGKM0();

  #pragma unroll
  for (int q = 0; q < 4; q++)
    #pragma unroll
    for (int j = 0; j < 8; j++)
      vt[(vcs + j) * 68 + q * 16 + vrow] = (unsigned short)vchunk[q][j];

  f32x4 s[4][4];
  #pragma unroll
  for (int i = 0; i < 4; i++)
    #pragma unroll
    for (int j = 0; j < 4; j++) s[i][j] = (f32x4)(0.f);
  #pragma unroll
  for (int mi = 0; mi < 4; mi++)
    #pragma unroll
    for (int nj = 0; nj < 4; nj++)
      s[mi][nj] = __builtin_amdgcn_mfma_f32_16x16x32_bf16(aq[mi], bk[nj], s[mi][nj], 0, 0, 0);

  const float scale = 0.17677669529663687f;
  #pragma unroll
  for (int mi = 0; mi < 4; mi++) {
    #pragma unroll
    for (int r = 0; r < 4; r++) {
      float t0 = s[mi][0][r] * scale, t1 = s[mi][1][r] * scale;
      float t2 = s[mi][2][r] * scale, t3 = s[mi][3][r] * scale;
      float mx = fmaxf(fmaxf(t0, t1), fmaxf(t2, t3));
      #pragma unroll
      for (int off = 8; off; off >>= 1) mx = fmaxf(mx, __shfl_xor(mx, off, 16));
      float e0 = expf(t0 - mx), e1 = expf(t1 - mx), e2 = expf(t2 - mx), e3 = expf(t3 - mx);
      float sm = e0 + e1 + e2 + e3;
      #pragma unroll
      for (int off = 8; off; off >>= 1) sm += __shfl_xor(sm, off, 16);
      float inv = 1.f / sm;
      int prow = mi * 16 + lk * 4 + r;
      ps[prow * 72 + lr + 0]  = f2bf(e0 * inv);
      ps[prow * 72 + lr + 16] = f2bf(e1 * inv);
      ps[prow * 72 + lr + 32] = f2bf(e2 * inv);
      ps[prow * 72 + lr + 48] = f2bf(e3 * inv);
    }
  }
  WAITLGKM0();

  f32x4 oacc[4][2];
  #pragma unroll
  for (int i = 0; i < 4; i++) { oacc[i][0] = (f32x4)(0.f); oacc[i][1] = (f32x4)(0.f); }
  #pragma unroll
  for (int kk = 0; kk < 2; kk++) {
    s16x8 bv[2];
    #pragma unroll
    for (int nf = 0; nf < 2; nf++)
      bv[nf] = *(const s16x8*)&vt[(nf * 16 + lr) * 68 + kk * 32 + lk * 8];
    #pragma unroll
    for (int mi = 0; mi < 4; mi++) {
      s16x8 ap = *(const s16x8*)&ps[(mi * 16 + lr) * 72 + kk * 32 + lk * 8];
      #pragma unroll
      for (int nf = 0; nf < 2; nf++)
        oacc[mi][nf] = __builtin_amdgcn_mfma_f32_16x16x32_bf16(ap, bv[nf], oacc[mi][nf], 0, 0, 0);
    }
  }
  #pragma unroll
  for (int mi = 0; mi < 4; mi++)
    #pragma unroll
    for (int nf = 0; nf < 2; nf++)
      #pragma unroll
      for (int r = 0; r < 4; r++) {
        int tok = mi * 16 + lk * 4 + r;
        int c = nf * 16 + lr;
        ob[(size_t)(b * 64 + tok) * 256 + h * 32 + c] = f2bf(oacc[mi][nf][r]);
      }
}

// -------- cluster probs -> log_emit via MFMA (e2 cancels in softmax) --------
// log_emit[t][k] = log(softmax_k((2*x.mt_k - |mt_k|^2)/T) + eps); the |x|^2
// term is constant over k and cancels. s = xb @ mtb^T via 16x16x32 MFMA:
// 4 waves x 64 tokens/block; B (mt bf16) in LDS [32][264]; A-frags straight
// from global (4 lanes of a row cover one 64B line per kk -> line-coalesced).
__global__ __launch_bounds__(256) void cluster_kernel(const unsigned short* __restrict__ xb,
                                                      const unsigned short* __restrict__ mtb,
                                                      const float* __restrict__ mtn,
                                                      float* __restrict__ log_emit) {
  __shared__ unsigned short ms[32 * 264];   // 16.5 KB
  const int t = threadIdx.x;
  for (int i = t; i < 2112; i += 256)
    ((uint2*)ms)[i] = ((const uint2*)mtb)[i];
  const int lane = t & 63, w = t >> 6;
  const int lr = lane & 15, lk = lane >> 4;
  const float mtn0 = mtn[lr], mtn1 = mtn[16 + lr];
  __syncthreads();

  const size_t tok0 = (size_t)blockIdx.x * 256 + (size_t)w * 64;
  f32x4 s[4][2];
  #pragma unroll
  for (int i = 0; i < 4; i++) { s[i][0] = (f32x4)(0.f); s[i][1] = (f32x4)(0.f); }

  #pragma unroll
  for (int kk = 0; kk < 8; kk++) {
    s16x8 bf0 = *(const s16x8*)&ms[lr * 264 + lk * 8 + kk * 32];
    s16x8 bf1 = *(const s16x8*)&ms[(16 + lr) * 264 + lk * 8 + kk * 32];
    #pragma unroll
    for (int mi = 0; mi < 4; mi++) {
      s16x8 af = *(const s16x8*)&xb[(tok0 + mi * 16 + lr) * 256 + lk * 8 + kk * 32];
      s[mi][0] = __builtin_amdgcn_mfma_f32_16x16x32_bf16(af, bf0, s[mi][0], 0, 0, 0);
      s[mi][1] = __builtin_amdgcn_mfma_f32_16x16x32_bf16(af, bf1, s[mi][1], 0, 0, 0);
    }
  }

  #pragma unroll
  for (int mi = 0; mi < 4; mi++) {
    #pragma unroll
    for (int r = 0; r < 4; r++) {
      float l0 = (2.f * s[mi][0][r] - mtn0) * 0.1f;
      float l1 = (2.f * s[mi][1][r] - mtn1) * 0.1f;
      float mx = fmaxf(l0, l1);
      #pragma unroll
      for (int off = 8; off; off >>= 1) mx = fmaxf(mx, __shfl_xor(mx, off, 16));
      float e0 = expf(l0 - mx), e1 = expf(l1 - mx);
      float sm = e0 + e1;
      #pragma unroll
      for (int off = 8; off; off >>= 1) sm += __shfl_xor(sm, off, 16);
      float inv = 1.f / sm;
      size_t row = tok0 + mi * 16 + lk * 4 + r;
      log_emit[row * 32 + lr]      = logf(e0 * inv + 1e-10f);
      log_emit[row * 32 + 16 + lr] = logf(e1 * inv + 1e-10f);
    }
  }
}

// ---------------- HMM forward scan + entropy ----------------
__global__ __launch_bounds__(256) void scan_kernel(const float* __restrict__ log_emit,
                                                   const float* __restrict__ pi,
                                                   const float* __restrict__ A,
                                                   float* __restrict__ cp,
                                                   float* __restrict__ ent) {
  const int g = threadIdx.x >> 5, j = threadIdx.x & 31;
  const int batch = blockIdx.x * 8 + g;
  float regA[32];
  #pragma unroll
  for (int i = 0; i < 32; i++) regA[i] = A[i * 32 + j];
  const float* le = log_emit + (size_t)batch * 64 * 32;
  float* cpo = cp + (size_t)batch * 64 * 32;

  float u = logf(pi[j] + 1e-10f) + le[j];
  float mx = u;
  #pragma unroll
  for (int off = 16; off; off >>= 1) mx = fmaxf(mx, __shfl_xor(mx, off, 32));
  float e = expf(u - mx), sm = e;
  #pragma unroll
  for (int off = 16; off; off >>= 1) sm += __shfl_xor(sm, off, 32);
  float p = e / sm;
  cpo[j] = p;
  float enta = p * logf(p + 1e-10f);

  for (int n = 1; n < 64; n++) {
    float tt = 0.f;
    #pragma unroll
    for (int i = 0; i < 32; i++) tt += __shfl(p, i, 32) * regA[i];
    u = logf(tt + 1e-10f) + le[n * 32 + j];
    mx = u;
    #pragma unroll
    for (int off = 16; off; off >>= 1) mx = fmaxf(mx, __shfl_xor(mx, off, 32));
    e = expf(u - mx); sm = e;
    #pragma unroll
    for (int off = 16; off; off >>= 1) sm += __shfl_xor(sm, off, 32);
    p = e / sm;
    cpo[n * 32 + j] = p;
    enta += p * logf(p + 1e-10f);
  }
  #pragma unroll
  for (int off = 16; off; off >>= 1) enta += __shfl_xor(enta, off, 32);
  if (j == 0) atomicAdd(ent, -enta * (1.f / (2048.f * 64.f)));
}

// ---------------- launcher ----------------
extern "C" void kernel_launch(void* const* d_in, const int* in_sizes, int n_in,
                              void* d_out, int out_size, void* d_ws, size_t ws_size,
                              hipStream_t stream) {
  const float* input = (const float*)d_in[0];
  const float* init_logits = (const float*)d_in[1];
  const float* trans = (const float*)d_in[2];
  const float* Wqkv = (const float*)d_in[3];
  const float* bqkv = (const float*)d_in[4];
  const float* Wo = (const float*)d_in[5];
  const float* bo = (const float*)d_in[6];
  const float* ln1g = (const float*)d_in[7];
  const float* ln1b = (const float*)d_in[8];
  const float* ln2g = (const float*)d_in[9];
  const float* ln2b = (const float*)d_in[10];
  const float* W1 = (const float*)d_in[11];
  const float* b1 = (const float*)d_in[12];
  const float* W2 = (const float*)d_in[13];
  const float* b2 = (const float*)d_in[14];
  const float* mus = (const float*)d_in[15];

  float* out = (float*)d_out;
  float* cp = out;                  // [BN,32]
  float* x = out + 4194304;         // emb_all [BN,256] f32 (written by final gemm_ln)
  float* d_pi = out + 37748736;
  float* d_A = out + 37748768;
  float* d_ent = out + 37749792;

  char* ws = (char*)d_ws;
  unsigned short* qkv = (unsigned short*)ws;        // region A: qkv -> hb -> log_emit
  unsigned short* hb = (unsigned short*)ws;
  float* log_emit = (float*)ws;
  unsigned short* ob = (unsigned short*)(ws + 268435456ull);   // region B
  unsigned short* xb = (unsigned short*)(ws + 335544320ull);   // residual stream bf16
  unsigned short* wq_b = (unsigned short*)(ws + 402653184ull);
  unsigned short* wo_b = (unsigned short*)(ws + 402653184ull + 786432ull);
  unsigned short* w1_b = (unsigned short*)(ws + 402653184ull + 1048576ull);
  unsigned short* w2_b = (unsigned short*)(ws + 402653184ull + 2097152ull);
  unsigned short* mtb = (unsigned short*)(ws + 402653184ull + 3145728ull);  // [32][264] bf16
  float* mtn = (float*)(ws + 402653184ull + 3178496ull);

  cvt_kernel<<<2048, 256, 0, stream>>>((const float4*)input, (ushort4*)xb, BNT * 256 / 4);
  cvtw_kernel<<<512, 256, 0, stream>>>((const float4*)Wqkv, (ushort4*)wq_b,
                                       (const float4*)Wo, (ushort4*)wo_b,
                                       (const float4*)W1, (ushort4*)w1_b,
                                       (const float4*)W2, (ushort4*)w2_b);
  mt_kernel<<<1, 64, 0, stream>>>(mus, mtb, mtn);
  piA_kernel<<<1, 64, 0, stream>>>(init_logits, trans, d_pi, d_A, d_ent);

  for (int l = 0; l < 2; l++) {
    gemm_nt<0><<<6144, 256, 0, stream>>>(xb, wq_b + l * 196608, bqkv + l * 768,
                                         qkv, 768, 256, 6);
    attn_kernel<<<16384, 64, 0, stream>>>(qkv, ob);
    gemm_ln<false><<<1024, 512, 0, stream>>>(ob, wo_b + l * 65536, bo + l * 256,
                                             xb, ln1g + l * 256, ln1b + l * 256,
                                             xb, nullptr, 256);
    gemm_nt<1><<<8192, 256, 0, stream>>>(xb, w1_b + l * 262144, b1 + l * 1024,
                                         hb, 1024, 256, 8);
    if (l == LLN - 1)
      gemm_ln<true><<<1024, 512, 0, stream>>>(hb, w2_b + l * 262144, b2 + l * 256,
                                              xb, ln2g + l * 256, ln2b + l * 256,
                                              xb, x, 1024);
    else
      gemm_ln<false><<<1024, 512, 0, stream>>>(hb, w2_b + l * 262144, b2 + l * 256,
                                               xb, ln2g + l * 256, ln2b + l * 256,
                                               xb, nullptr, 1024);
  }

  cluster_kernel<<<512, 256, 0, stream>>>(xb, mtb, mtn, log_emit);
  scan_kernel<<<256, 256, 0, stream>>>(log_emit, d_pi, d_A, cp, d_ent);
}